// Round 2
// baseline (28149.930 us; speedup 1.0000x reference)
//
#include <hip/hip_runtime.h>
#include <cstdint>
#include <cstddef>

// ---------------------------------------------------------------------------
// GCNLSTMRawPluginGenderHanded: full-network forward on MI355X.
//  x_in[1024,8500] --LSTM(3 layers, H=640, seq=nodes)--> [1024,640]
//  --4x(GCNConv -> leaky_relu -> BN)--> [1024,50] --segment_sum(64)-->
//  [16,50] ++ gender,handed --3xFC--> [16,1]
//
// Strategy:
//  - big input projections as f16 MFMA GEMMs (m97-structure 128^2 tile)
//  - LSTM recurrence: persistent 20-block kernel, Whh register-resident as
//    packed f16, v_dot2_f32_f16 matvec, hand-rolled agent-scope barrier/step
//  - GCN aggregation via device-built CSR (gather, no per-feature atomics)
// ---------------------------------------------------------------------------

typedef _Float16 f16;
typedef __attribute__((ext_vector_type(2))) _Float16 f16x2;
typedef __attribute__((ext_vector_type(8))) _Float16 f16x8;
typedef __attribute__((ext_vector_type(4))) float f32x4;

#define DEVFN static __device__ __forceinline__

DEVFN unsigned pkh2(float a, float b) {
  unsigned short lo = __builtin_bit_cast(unsigned short, (_Float16)a);
  unsigned short hi = __builtin_bit_cast(unsigned short, (_Float16)b);
  return ((unsigned)hi << 16) | (unsigned)lo;
}
DEVFN float fdot2u(unsigned a, unsigned b, float c) {
  return __builtin_amdgcn_fdot2(__builtin_bit_cast(f16x2, a),
                                __builtin_bit_cast(f16x2, b), c, false);
}
DEVFN float sigm(float x) { return 1.0f / (1.0f + __expf(-x)); }
DEVFN float tanh_(float x) {
  float a = fabsf(x);
  float e = __expf(-2.0f * a);          // e in (0,1], never overflows
  float t = (1.0f - e) / (1.0f + e);
  return x < 0.0f ? -t : t;
}

// ---------------- convert fp32 -> f16 with K padding (zeros) ---------------
__global__ void k_cvt_pad(const float* __restrict__ src, f16* __restrict__ dst,
                          int K, int KP) {
  int r = blockIdx.y;
  int k = blockIdx.x * 256 + threadIdx.x;
  if (k >= KP) return;
  float v = (k < K) ? src[(size_t)r * K + k] : 0.0f;
  dst[(size_t)r * KP + k] = (f16)v;
}

__global__ void k_vadd(const float* __restrict__ a, const float* __restrict__ b,
                       float* __restrict__ o, int n) {
  int i = blockIdx.x * 256 + threadIdx.x;
  if (i < n) o[i] = a[i] + b[i];
}

__global__ void k_zero(int* __restrict__ p, int n) {
  int i = blockIdx.x * 256 + threadIdx.x;
  if (i < n) p[i] = 0;
}

// ---------------- f16 MFMA GEMM: C[M,N] = A[M,K] * B[N,K]^T + bias[N] ------
// m97 structure: 128x128 tile, BK=32, 4 waves (2x2 of 64x64), 16x16x32 MFMA,
// global_load_lds width 16.  M,N multiples of 128, K multiple of 32.
__global__ __launch_bounds__(256, 2) void k_gemm_bt_f16(
    const f16* __restrict__ A, const f16* __restrict__ B,
    const float* __restrict__ bias, float* __restrict__ C,
    int M, int N, int K) {
  __shared__ __align__(16) f16 As[128 * 32];
  __shared__ __align__(16) f16 Bs[128 * 32];
  const int tid = threadIdx.x;
  const int wave = tid >> 6, lane = tid & 63;
  const int l15 = lane & 15, l4 = lane >> 4;
  const int bm = blockIdx.y * 128, bn = blockIdx.x * 128;
  const int wm = (wave >> 1) * 64, wn = (wave & 1) * 64;
  const int srow = tid >> 2;          // staging: row within 64-row half-tile
  const int skk = (tid & 3) * 8;      // staging: k offset (8 f16 = 16B)
  f32x4 acc[4][4] = {};
  for (int k0 = 0; k0 < K; k0 += 32) {
    __syncthreads();  // protect LDS against previous iteration readers
#pragma unroll
    for (int i = 0; i < 2; ++i) {
      const f16* ga = A + (size_t)(bm + i * 64 + srow) * K + (k0 + skk);
      const f16* gb = B + (size_t)(bn + i * 64 + srow) * K + (k0 + skk);
      char* la = (char*)As + i * 4096 + wave * 1024;  // wave-uniform LDS base
      char* lb = (char*)Bs + i * 4096 + wave * 1024;
      __builtin_amdgcn_global_load_lds(
          (const __attribute__((address_space(1))) void*)ga,
          (__attribute__((address_space(3))) void*)la, 16, 0, 0);
      __builtin_amdgcn_global_load_lds(
          (const __attribute__((address_space(1))) void*)gb,
          (__attribute__((address_space(3))) void*)lb, 16, 0, 0);
    }
    __syncthreads();  // drains vmcnt (global_load_lds) + lgkm
    f16x8 af[4], bf[4];
#pragma unroll
    for (int mi = 0; mi < 4; ++mi)
      af[mi] = *(const f16x8*)&As[(wm + mi * 16 + l15) * 32 + l4 * 8];
#pragma unroll
    for (int nj = 0; nj < 4; ++nj)
      bf[nj] = *(const f16x8*)&Bs[(wn + nj * 16 + l15) * 32 + l4 * 8];
#pragma unroll
    for (int mi = 0; mi < 4; ++mi)
#pragma unroll
      for (int nj = 0; nj < 4; ++nj)
        acc[mi][nj] = __builtin_amdgcn_mfma_f32_16x16x32_f16(
            af[mi], bf[nj], acc[mi][nj], 0, 0, 0);
  }
#pragma unroll
  for (int mi = 0; mi < 4; ++mi) {
#pragma unroll
    for (int nj = 0; nj < 4; ++nj) {
      int row = bm + wm + mi * 16 + l4 * 4;
      int col = bn + wn + nj * 16 + l15;
      float bv = bias[col];
#pragma unroll
      for (int j = 0; j < 4; ++j)
        C[(size_t)(row + j) * N + col] = acc[mi][nj][j] + bv;
    }
  }
}

// ---------------- persistent LSTM recurrence -------------------------------
// 20 blocks x 512 threads. Block b owns h-dims [b*32, b*32+32) (=> 128 gate
// rows). Thread t: slice = t&15 (40 cols), rowg = t>>4 (one h-dim, 4 gates).
// Weights: 4 gates x 20 packed-f16 pairs = 80 VGPRs, loaded once.
// Per step: stage h_{t-1} (global->LDS as half2), dot2 matvec, shfl reduce
// over 16 slices, gates on slice==0 lanes, write h, agent-scope barrier.
#define RB 20
__global__ __launch_bounds__(512, 2) void k_lstm(
    const float* __restrict__ Whh,   // [2560][640] fp32
    const float* __restrict__ xw,    // [1024][2560] fp32: x@Wih^T + bih + bhh
    float* __restrict__ hseq,        // [1024][640] out fp32
    f16* __restrict__ hseq16,        // [1024][640] out f16 (next-layer GEMM)
    unsigned* __restrict__ ctr) {
  __shared__ unsigned h2s[320];  // h_{t-1} as packed half2
  const int tid = threadIdx.x;
  const int slice = tid & 15;
  const int rowg = tid >> 4;                 // 0..31
  const int dim = blockIdx.x * 32 + rowg;    // owned h-dim
  const int c0 = slice * 40;
  unsigned w[4][20];
#pragma unroll
  for (int g = 0; g < 4; ++g) {
    const float* wr = Whh + (size_t)(g * 640 + dim) * 640 + c0;
#pragma unroll
    for (int c = 0; c < 20; ++c) {
      float2 f = *(const float2*)(wr + 2 * c);
      w[g][c] = pkh2(f.x, f.y);
    }
  }
  const bool isred = (slice == 0);
  float creg = 0.0f;
  for (int t = 0; t < 1024; ++t) {
    // prefetch this step's input-projection values (independent of barrier)
    float xwv0 = 0, xwv1 = 0, xwv2 = 0, xwv3 = 0;
    if (isred) {
      const float* xr = xw + (size_t)t * 2560 + dim;
      xwv0 = xr[0]; xwv1 = xr[640]; xwv2 = xr[1280]; xwv3 = xr[1920];
    }
    if (t > 0) {
      if (tid == 0) {
        unsigned target = (unsigned)(RB * t);
        while (__hip_atomic_load(ctr, __ATOMIC_ACQUIRE,
                                 __HIP_MEMORY_SCOPE_AGENT) < target)
          __builtin_amdgcn_s_sleep(1);
      }
      __syncthreads();
      __threadfence();  // acquire: invalidate caches before reading h_{t-1}
    }
    if (tid < 320) {
      unsigned p = 0;
      if (t > 0) {
        float2 f = *(const float2*)(hseq + (size_t)(t - 1) * 640 + tid * 2);
        p = pkh2(f.x, f.y);
      }
      h2s[tid] = p;
    }
    __syncthreads();
    float a0 = 0, a1 = 0, a2 = 0, a3 = 0;
#pragma unroll
    for (int c = 0; c < 20; ++c) {
      unsigned hv = h2s[slice * 20 + c];
      a0 = fdot2u(w[0][c], hv, a0);
      a1 = fdot2u(w[1][c], hv, a1);
      a2 = fdot2u(w[2][c], hv, a2);
      a3 = fdot2u(w[3][c], hv, a3);
    }
#pragma unroll
    for (int m = 1; m < 16; m <<= 1) {
      a0 += __shfl_xor(a0, m, 64);
      a1 += __shfl_xor(a1, m, 64);
      a2 += __shfl_xor(a2, m, 64);
      a3 += __shfl_xor(a3, m, 64);
    }
    if (isred) {
      float gi = sigm(xwv0 + a0);
      float gf = sigm(xwv1 + a1);
      float gg = tanh_(xwv2 + a2);
      float go = sigm(xwv3 + a3);
      creg = gf * creg + gi * gg;
      float h = go * tanh_(creg);
      hseq[(size_t)t * 640 + dim] = h;
      hseq16[(size_t)t * 640 + dim] = (f16)h;
    }
    __threadfence();  // release: push h stores to device visibility
    __syncthreads();
    if (tid == 0)
      __hip_atomic_fetch_add(ctr, 1u, __ATOMIC_RELEASE,
                             __HIP_MEMORY_SCOPE_AGENT);
  }
}

// ---------------- CSR build (edges + self-loops), degrees ------------------
#define NE 16384
#define NN 1024
#define NET (NE + NN)

__global__ void k_csr_count(const int* __restrict__ ei, int* __restrict__ cnt) {
  int i = blockIdx.x * 256 + threadIdx.x;
  if (i >= NET) return;
  int d = (i < NE) ? ei[NE + i] : (i - NE);
  atomicAdd(&cnt[d], 1);
}

__global__ __launch_bounds__(1024) void k_csr_scan(
    const int* __restrict__ cnt, int* __restrict__ offs,
    float* __restrict__ dinv) {
  __shared__ int sd[1024];
  int tid = threadIdx.x;
  int v = cnt[tid];
  dinv[tid] = rsqrtf((float)v);  // deg >= 1 via self-loops
  sd[tid] = v;
  __syncthreads();
  for (int o = 1; o < 1024; o <<= 1) {
    int t = (tid >= o) ? sd[tid - o] : 0;
    __syncthreads();
    sd[tid] += t;
    __syncthreads();
  }
  if (tid == 0) offs[0] = 0;
  offs[tid + 1] = sd[tid];
}

__global__ void k_csr_fill(const int* __restrict__ ei, const int* __restrict__ offs,
                           int* __restrict__ fillc, const float* __restrict__ dinv,
                           int* __restrict__ asrc, float* __restrict__ anrm) {
  int i = blockIdx.x * 256 + threadIdx.x;
  if (i >= NET) return;
  int s, d;
  if (i < NE) { s = ei[i]; d = ei[NE + i]; }
  else        { s = d = i - NE; }
  int pos = offs[d] + atomicAdd(&fillc[d], 1);
  asrc[pos] = s;
  anrm[pos] = dinv[s] * dinv[d];
}

// ---------------- small fp32 GEMM: C[M,N] = A[M,K] * W[K,N] ----------------
__global__ void k_gemm_f32(const float* __restrict__ A, const float* __restrict__ W,
                           float* __restrict__ C, int M, int K, int N) {
  int n = blockIdx.x * 64 + threadIdx.x;
  int m = blockIdx.y * 4 + threadIdx.y;
  if (n >= N || m >= M) return;
  const float* ar = A + (size_t)m * K;
  float acc = 0.0f;
#pragma unroll 4
  for (int k = 0; k < K; ++k) acc = fmaf(ar[k], W[(size_t)k * N + n], acc);
  C[(size_t)m * N + n] = acc;
}

// ---------------- GCN aggregation (gather over CSR) + bias + leaky ---------
__global__ void k_gcn_agg(const float* __restrict__ h, const int* __restrict__ asrc,
                          const float* __restrict__ anrm, const int* __restrict__ offs,
                          const float* __restrict__ b, float* __restrict__ out,
                          int F) {
  int n = blockIdx.x, f = threadIdx.x;
  if (f >= F) return;
  int e0 = offs[n], e1 = offs[n + 1];
  float acc = 0.0f;
  for (int e = e0; e < e1; ++e)
    acc = fmaf(anrm[e], h[(size_t)asrc[e] * F + f], acc);
  acc += b[f];
  out[(size_t)n * F + f] = acc > 0.0f ? acc : 0.01f * acc;
}

// ---------------- batch norm (train-mode, no affine, biased var) -----------
__global__ void k_bn_stats(const float* __restrict__ x, float* __restrict__ mean,
                           float* __restrict__ rstd, int F) {
  int f = blockIdx.x, tid = threadIdx.x;  // 256 threads
  float s = 0, s2 = 0;
  for (int n = tid; n < 1024; n += 256) {
    float v = x[(size_t)n * F + f];
    s += v;
    s2 += v * v;
  }
#pragma unroll
  for (int m = 1; m < 64; m <<= 1) {
    s += __shfl_xor(s, m, 64);
    s2 += __shfl_xor(s2, m, 64);
  }
  __shared__ float ls[4], ls2[4];
  int wv = tid >> 6;
  if ((tid & 63) == 0) { ls[wv] = s; ls2[wv] = s2; }
  __syncthreads();
  if (tid == 0) {
    float S = ls[0] + ls[1] + ls[2] + ls[3];
    float S2 = ls2[0] + ls2[1] + ls2[2] + ls2[3];
    float mu = S * (1.0f / 1024.0f);
    float var = S2 * (1.0f / 1024.0f) - mu * mu;
    mean[f] = mu;
    rstd[f] = rsqrtf(var + 1e-5f);
  }
}

__global__ void k_bn_apply(float* __restrict__ x, const float* __restrict__ mean,
                           const float* __restrict__ rstd, int F) {
  int f = blockIdx.x * 256 + threadIdx.x;
  int n = blockIdx.y;
  if (f < F) {
    size_t i = (size_t)n * F + f;
    x[i] = (x[i] - mean[f]) * rstd[f];
  }
}

// ---------------- segment_sum + concat + 3x FC -----------------------------
__global__ __launch_bounds__(1024) void k_segfcn(
    const float* __restrict__ x,  // [1024][50]
    const float* __restrict__ gender, const float* __restrict__ handed,
    const float* __restrict__ W1, const float* __restrict__ b1,   // [32][52]
    const float* __restrict__ W2, const float* __restrict__ b2,   // [16][32]
    const float* __restrict__ W3, const float* __restrict__ b3,   // [1][16]
    float* __restrict__ out) {
  __shared__ float seg[16][52];
  __shared__ float y1[16][32];
  __shared__ float y2[16][16];
  int tid = threadIdx.x;
  if (tid < 800) {
    int g = tid / 50, f = tid % 50;
    float s = 0;
    for (int i = 0; i < 64; ++i) s += x[(size_t)(g * 64 + i) * 50 + f];
    seg[g][f] = s;
  }
  if (tid < 16) { seg[tid][50] = gender[tid]; seg[tid][51] = handed[tid]; }
  __syncthreads();
  if (tid < 512) {
    int g = tid >> 5, o = tid & 31;
    float s = b1[o];
    for (int k = 0; k < 52; ++k) s += seg[g][k] * W1[o * 52 + k];
    y1[g][o] = s;
  }
  __syncthreads();
  if (tid < 256) {
    int g = tid >> 4, o = tid & 15;
    float s = b2[o];
    for (int k = 0; k < 32; ++k) s += y1[g][k] * W2[o * 32 + k];
    y2[g][o] = s;
  }
  __syncthreads();
  if (tid < 16) {
    float s = b3[0];
    for (int k = 0; k < 16; ++k) s += y2[tid][k] * W3[k];
    out[tid] = s;
  }
}

// ---------------------------------------------------------------------------
extern "C" void kernel_launch(void* const* d_in, const int* in_sizes, int n_in,
                              void* d_out, int out_size, void* d_ws, size_t ws_size,
                              hipStream_t stream) {
  const float* x_in   = (const float*)d_in[0];
  const int*   ei     = (const int*)d_in[1];
  const float* gender = (const float*)d_in[2];
  const float* handed = (const float*)d_in[3];
  const float* Wih[3] = {(const float*)d_in[4],  (const float*)d_in[8],  (const float*)d_in[12]};
  const float* Whh[3] = {(const float*)d_in[5],  (const float*)d_in[9],  (const float*)d_in[13]};
  const float* bih[3] = {(const float*)d_in[6],  (const float*)d_in[10], (const float*)d_in[14]};
  const float* bhh[3] = {(const float*)d_in[7],  (const float*)d_in[11], (const float*)d_in[15]};
  const float* gW[4]  = {(const float*)d_in[16], (const float*)d_in[18], (const float*)d_in[20], (const float*)d_in[22]};
  const float* gb[4]  = {(const float*)d_in[17], (const float*)d_in[19], (const float*)d_in[21], (const float*)d_in[23]};
  const float* fW[3]  = {(const float*)d_in[24], (const float*)d_in[26], (const float*)d_in[28]};
  const float* fb[3]  = {(const float*)d_in[25], (const float*)d_in[27], (const float*)d_in[29]};
  float* out = (float*)d_out;

  // workspace layout
  char* ws = (char*)d_ws;
  size_t off = 0;
  auto alloc = [&](size_t bytes) -> void* {
    void* p = ws + off;
    off = (off + bytes + 255) & ~(size_t)255;
    return p;
  };
  const int KP0 = 8512;  // 8500 padded to /32
  f16*   X16   = (f16*)alloc((size_t)1024 * KP0 * 2);
  f16*   W016  = (f16*)alloc((size_t)2560 * KP0 * 2);
  f16*   W116  = (f16*)alloc((size_t)2560 * 640 * 2);
  f16*   W216  = (f16*)alloc((size_t)2560 * 640 * 2);
  float* BSUM  = (float*)alloc(3 * 2560 * 4);
  float* XW    = (float*)alloc((size_t)1024 * 2560 * 4);
  float* HS0   = (float*)alloc((size_t)1024 * 640 * 4);
  f16*   HS0H  = (f16*)alloc((size_t)1024 * 640 * 2);
  float* HS1   = (float*)alloc((size_t)1024 * 640 * 4);
  f16*   HS1H  = (f16*)alloc((size_t)1024 * 640 * 2);
  float* HS2   = (float*)alloc((size_t)1024 * 640 * 4);
  f16*   HS2H  = (f16*)alloc((size_t)1024 * 640 * 2);
  float* GA    = (float*)alloc((size_t)1024 * 320 * 4);
  float* GB    = (float*)alloc((size_t)1024 * 320 * 4);
  int*   CNT   = (int*)alloc(1024 * 4);
  int*   OFFS  = (int*)alloc(1025 * 4);
  int*   FILLC = (int*)alloc(1024 * 4);
  float* DINV  = (float*)alloc(1024 * 4);
  int*   ASRC  = (int*)alloc(NET * 4);
  float* ANRM  = (float*)alloc(NET * 4);
  float* MEAN  = (float*)alloc(320 * 4);
  float* RSTD  = (float*)alloc(320 * 4);
  unsigned* CTR = (unsigned*)alloc(256);  // 3 counters, 64B apart
  (void)ws_size; (void)in_sizes; (void)n_in; (void)out_size;

  // conversions & bias sums
  k_cvt_pad<<<dim3(34, 1024), 256, 0, stream>>>(x_in, X16, 8500, KP0);
  k_cvt_pad<<<dim3(34, 2560), 256, 0, stream>>>(Wih[0], W016, 8500, KP0);
  k_cvt_pad<<<dim3(3, 2560), 256, 0, stream>>>(Wih[1], W116, 640, 640);
  k_cvt_pad<<<dim3(3, 2560), 256, 0, stream>>>(Wih[2], W216, 640, 640);
  for (int l = 0; l < 3; ++l)
    k_vadd<<<10, 256, 0, stream>>>(bih[l], bhh[l], BSUM + l * 2560, 2560);

  // zero counters (ws is poisoned 0xAA each timed call)
  k_zero<<<5, 256, 0, stream>>>(CNT, 1024);
  k_zero<<<5, 256, 0, stream>>>(FILLC, 1024);
  k_zero<<<1, 64, 0, stream>>>((int*)CTR, 64);

  // CSR build
  k_csr_count<<<68, 256, 0, stream>>>(ei, CNT);
  k_csr_scan<<<1, 1024, 0, stream>>>(CNT, OFFS, DINV);
  k_csr_fill<<<68, 256, 0, stream>>>(ei, OFFS, FILLC, DINV, ASRC, ANRM);

  // LSTM: layer 0
  k_gemm_bt_f16<<<dim3(20, 8), 256, 0, stream>>>(X16, W016, BSUM, XW, 1024, 2560, KP0);
  k_lstm<<<RB, 512, 0, stream>>>(Whh[0], XW, HS0, HS0H, CTR);
  // layer 1
  k_gemm_bt_f16<<<dim3(20, 8), 256, 0, stream>>>(HS0H, W116, BSUM + 2560, XW, 1024, 2560, 640);
  k_lstm<<<RB, 512, 0, stream>>>(Whh[1], XW, HS1, HS1H, CTR + 16);
  // layer 2
  k_gemm_bt_f16<<<dim3(20, 8), 256, 0, stream>>>(HS1H, W216, BSUM + 5120, XW, 1024, 2560, 640);
  k_lstm<<<RB, 512, 0, stream>>>(Whh[2], XW, HS2, HS2H, CTR + 32);

  // GCN stack
  const float* gin = HS2;
  int Fin = 640;
  const int Fo[4] = {320, 180, 90, 50};
  for (int l = 0; l < 4; ++l) {
    int F = Fo[l];
    k_gemm_f32<<<dim3((F + 63) / 64, 256), dim3(64, 4), 0, stream>>>(gin, gW[l], GA, 1024, Fin, F);
    k_gcn_agg<<<1024, ((F + 63) / 64) * 64, 0, stream>>>(GA, ASRC, ANRM, OFFS, gb[l], GB, F);
    k_bn_stats<<<F, 256, 0, stream>>>(GB, MEAN, RSTD, F);
    k_bn_apply<<<dim3((F + 255) / 256, 1024), 256, 0, stream>>>(GB, MEAN, RSTD, F);
    gin = GB;
    Fin = F;
  }

  // readout
  k_segfcn<<<1, 1024, 0, stream>>>(GB, gender, handed, fW[0], fb[0], fW[1], fb[1], fW[2], fb[2], out);
}

// Round 6
// 10141.588 us; speedup vs baseline: 2.7757x; 2.7757x over previous
//
#include <hip/hip_runtime.h>
#include <cstdint>
#include <cstddef>

// ---------------------------------------------------------------------------
// GCNLSTMRawPluginGenderHanded: full-network forward on MI355X.
//  x_in[1024,8500] --LSTM(3 layers, H=640, seq=nodes)--> [1024,640]
//  --4x(GCNConv -> leaky_relu -> BN)--> [1024,50] --segment_sum(64)-->
//  [16,50] ++ gender,handed --3xFC--> [16,1]
//
// Strategy:
//  - big input projections as f16 MFMA GEMMs (m97-structure 128^2 tile)
//  - LSTM recurrence: persistent 20-block kernel, Whh register-resident as
//    packed f16, v_dot2_f32_f16 matvec. Cross-block sync via DIRECT-TO-LLC
//    accesses (sc0 sc1 = bypass L1+L2; LLC is shared/coherent across XCDs).
//    NO cache-maintenance fences (round-2's buffer_inv/wbl2 = 8.7us/step).
//    All spins bounded + sticky dead-flag: failure -> signature, not hang.
//  - GCN aggregation via device-built CSR (gather, no per-feature atomics)
// ---------------------------------------------------------------------------

typedef _Float16 f16;
typedef __attribute__((ext_vector_type(2))) _Float16 f16x2;
typedef __attribute__((ext_vector_type(8))) _Float16 f16x8;
typedef __attribute__((ext_vector_type(4))) float f32x4;

#define DEVFN static __device__ __forceinline__

DEVFN unsigned pkh2(float a, float b) {
  unsigned short lo = __builtin_bit_cast(unsigned short, (_Float16)a);
  unsigned short hi = __builtin_bit_cast(unsigned short, (_Float16)b);
  return ((unsigned)hi << 16) | (unsigned)lo;
}
DEVFN float fdot2u(unsigned a, unsigned b, float c) {
  return __builtin_amdgcn_fdot2(__builtin_bit_cast(f16x2, a),
                                __builtin_bit_cast(f16x2, b), c, false);
}
DEVFN float sigm(float x) { return 1.0f / (1.0f + __expf(-x)); }
DEVFN float tanh_(float x) {
  float a = fabsf(x);
  float e = __expf(-2.0f * a);          // e in (0,1], never overflows
  float t = (1.0f - e) / (1.0f + e);
  return x < 0.0f ? -t : t;
}

// ---- direct-to-LLC communication helpers ----------------------------------
// sc0 sc1 on loads/stores: bypass L1 and per-XCD L2, access the die-level
// LLC (shared by all XCDs). sc1 on atomics: execute at device scope (LLC).
// This gives cross-XCD visibility with NO buffer_inv/buffer_wbl2.
DEVFN void st_llc_f32(float* p, float v) {
  asm volatile("global_store_dword %0, %1, off sc0 sc1"
               :: "v"(p), "v"(v) : "memory");
}
DEVFN float2 ld_llc_f32x2(const float* p) {
  float2 v;
  asm volatile("global_load_dwordx2 %0, %1, off sc0 sc1\n\ts_waitcnt vmcnt(0)"
               : "=v"(v) : "v"(p) : "memory");
  return v;
}
DEVFN unsigned ld_llc_u32(const unsigned* p) {
  unsigned v;
  asm volatile("global_load_dword %0, %1, off sc0 sc1\n\ts_waitcnt vmcnt(0)"
               : "=v"(v) : "v"(p) : "memory");
  return v;
}
DEVFN void atom_add_llc(unsigned* p, unsigned v) {
  asm volatile("global_atomic_add %0, %1, off sc1"
               :: "v"(p), "v"(v) : "memory");
}
DEVFN void wait_vm0() {
  asm volatile("s_waitcnt vmcnt(0)" ::: "memory");
}

// ---------------- convert fp32 -> f16 with K padding (zeros) ---------------
__global__ void k_cvt_pad(const float* __restrict__ src, f16* __restrict__ dst,
                          int K, int KP) {
  int r = blockIdx.y;
  int k = blockIdx.x * 256 + threadIdx.x;
  if (k >= KP) return;
  float v = (k < K) ? src[(size_t)r * K + k] : 0.0f;
  dst[(size_t)r * KP + k] = (f16)v;
}

__global__ void k_vadd(const float* __restrict__ a, const float* __restrict__ b,
                       float* __restrict__ o, int n) {
  int i = blockIdx.x * 256 + threadIdx.x;
  if (i < n) o[i] = a[i] + b[i];
}

__global__ void k_zero(int* __restrict__ p, int n) {
  int i = blockIdx.x * 256 + threadIdx.x;
  if (i < n) p[i] = 0;
}

// ---------------- f16 MFMA GEMM: C[M,N] = A[M,K] * B[N,K]^T + bias[N] ------
__global__ __launch_bounds__(256, 2) void k_gemm_bt_f16(
    const f16* __restrict__ A, const f16* __restrict__ B,
    const float* __restrict__ bias, float* __restrict__ C,
    int M, int N, int K) {
  __shared__ __align__(16) f16 As[128 * 32];
  __shared__ __align__(16) f16 Bs[128 * 32];
  const int tid = threadIdx.x;
  const int wave = tid >> 6, lane = tid & 63;
  const int l15 = lane & 15, l4 = lane >> 4;
  const int bm = blockIdx.y * 128, bn = blockIdx.x * 128;
  const int wm = (wave >> 1) * 64, wn = (wave & 1) * 64;
  const int srow = tid >> 2;          // staging: row within 64-row half-tile
  const int skk = (tid & 3) * 8;      // staging: k offset (8 f16 = 16B)
  f32x4 acc[4][4] = {};
  for (int k0 = 0; k0 < K; k0 += 32) {
    __syncthreads();  // protect LDS against previous iteration readers
#pragma unroll
    for (int i = 0; i < 2; ++i) {
      const f16* ga = A + (size_t)(bm + i * 64 + srow) * K + (k0 + skk);
      const f16* gb = B + (size_t)(bn + i * 64 + srow) * K + (k0 + skk);
      char* la = (char*)As + i * 4096 + wave * 1024;  // wave-uniform LDS base
      char* lb = (char*)Bs + i * 4096 + wave * 1024;
      __builtin_amdgcn_global_load_lds(
          (const __attribute__((address_space(1))) void*)ga,
          (__attribute__((address_space(3))) void*)la, 16, 0, 0);
      __builtin_amdgcn_global_load_lds(
          (const __attribute__((address_space(1))) void*)gb,
          (__attribute__((address_space(3))) void*)lb, 16, 0, 0);
    }
    __syncthreads();  // drains vmcnt (global_load_lds) + lgkm
    f16x8 af[4], bf[4];
#pragma unroll
    for (int mi = 0; mi < 4; ++mi)
      af[mi] = *(const f16x8*)&As[(wm + mi * 16 + l15) * 32 + l4 * 8];
#pragma unroll
    for (int nj = 0; nj < 4; ++nj)
      bf[nj] = *(const f16x8*)&Bs[(wn + nj * 16 + l15) * 32 + l4 * 8];
#pragma unroll
    for (int mi = 0; mi < 4; ++mi)
#pragma unroll
      for (int nj = 0; nj < 4; ++nj)
        acc[mi][nj] = __builtin_amdgcn_mfma_f32_16x16x32_f16(
            af[mi], bf[nj], acc[mi][nj], 0, 0, 0);
  }
#pragma unroll
  for (int mi = 0; mi < 4; ++mi) {
#pragma unroll
    for (int nj = 0; nj < 4; ++nj) {
      int row = bm + wm + mi * 16 + l4 * 4;
      int col = bn + wn + nj * 16 + l15;
      float bv = bias[col];
#pragma unroll
      for (int j = 0; j < 4; ++j)
        C[(size_t)(row + j) * N + col] = acc[mi][nj][j] + bv;
    }
  }
}

// ---------------- persistent LSTM recurrence (LLC-synced) ------------------
// 20 blocks x 512 threads. Block b owns h-dims [b*32, b*32+32) (=> 128 gate
// rows). Thread t: slice = t&15 (40 cols), rowg = t>>4 (one h-dim, 4 gates).
// Weights: 4 gates x 20 packed-f16 pairs = 80 VGPRs, loaded once.
// Per step: poll step-counter (LLC), stage h_{t-1} to LDS (LLC loads), dot2
// matvec, shfl-reduce over 16 slices, gates, publish h (LLC store) + counter
// add (LLC atomic). No fences, no cache maintenance. Spins bounded (sticky
// dead-flag) so any protocol failure finishes with a diagnostic signature.
// sy[32] = step counter (own 128B line).
#define RB 20
__global__ __launch_bounds__(512, 2) void k_lstm(
    const float* __restrict__ Whh,   // [2560][640] fp32
    const float* __restrict__ xw,    // [1024][2560] fp32: x@Wih^T + bih + bhh
    float* __restrict__ hseq,        // [1024][640] out fp32
    f16* __restrict__ hseq16,        // [1024][640] out f16 (next-layer GEMM)
    unsigned* __restrict__ sy) {
  __shared__ unsigned h2s[320];  // h_{t-1} as packed half2
  const int tid = threadIdx.x;
  unsigned* stepc = sy + 32;

  const int slice = tid & 15;
  const int rowg = tid >> 4;                    // 0..31
  const int dim = blockIdx.x * 32 + rowg;       // owned h-dim
  const int c0 = slice * 40;
  unsigned w[4][20];
#pragma unroll
  for (int g = 0; g < 4; ++g) {
    const float* wr = Whh + (size_t)(g * 640 + dim) * 640 + c0;
#pragma unroll
    for (int c = 0; c < 20; ++c) {
      float2 f = *(const float2*)(wr + 2 * c);
      w[g][c] = pkh2(f.x, f.y);
    }
  }
  const bool isred = (slice == 0);
  float creg = 0.0f;
  int dead = 0;  // sticky: set if a step-poll times out (diagnostic mode)
  for (int t = 0; t < 1024; ++t) {
    // prefetch this step's input-projection values (independent of barrier)
    float xwv0 = 0, xwv1 = 0, xwv2 = 0, xwv3 = 0;
    if (isred) {
      const float* xr = xw + (size_t)t * 2560 + dim;
      xwv0 = xr[0]; xwv1 = xr[640]; xwv2 = xr[1280]; xwv3 = xr[1920];
    }
    if (t > 0 && !dead) {
      // all lanes poll the same dword (coalesces to one LLC request per wave)
      const unsigned target = (unsigned)(RB * t);
      int spins = 0;
      while (ld_llc_u32(stepc) < target) {
        if (++spins > 1000000) { dead = 1; break; }  // ~0.2s cap, run free
      }
    }
    if (tid < 320) {
      unsigned p = 0;
      if (t > 0) {
        float2 f = ld_llc_f32x2(hseq + (size_t)(t - 1) * 640 + tid * 2);
        p = pkh2(f.x, f.y);
      }
      h2s[tid] = p;
    }
    __syncthreads();
    float a0 = 0, a1 = 0, a2 = 0, a3 = 0;
#pragma unroll
    for (int c = 0; c < 20; ++c) {
      unsigned hv = h2s[slice * 20 + c];
      a0 = fdot2u(w[0][c], hv, a0);
      a1 = fdot2u(w[1][c], hv, a1);
      a2 = fdot2u(w[2][c], hv, a2);
      a3 = fdot2u(w[3][c], hv, a3);
    }
#pragma unroll
    for (int m = 1; m < 16; m <<= 1) {
      a0 += __shfl_xor(a0, m, 64);
      a1 += __shfl_xor(a1, m, 64);
      a2 += __shfl_xor(a2, m, 64);
      a3 += __shfl_xor(a3, m, 64);
    }
    if (isred) {
      float gi = sigm(xwv0 + a0);
      float gf = sigm(xwv1 + a1);
      float gg = tanh_(xwv2 + a2);
      float go = sigm(xwv3 + a3);
      creg = gf * creg + gi * gg;
      float h = go * tanh_(creg);
      st_llc_f32(hseq + (size_t)t * 640 + dim, h);   // publish via LLC
      hseq16[(size_t)t * 640 + dim] = (f16)h;        // not read intra-kernel
    }
    wait_vm0();        // per-wave: h stores have reached the LLC
    __syncthreads();   // whole block's stores are visible
    if (tid == 0) atom_add_llc(stepc, 1u);  // device-scope signal at LLC
  }
}

// ---------------- CSR build (edges + self-loops), degrees ------------------
#define NE 16384
#define NN 1024
#define NET (NE + NN)

__global__ void k_csr_count(const int* __restrict__ ei, int* __restrict__ cnt) {
  int i = blockIdx.x * 256 + threadIdx.x;
  if (i >= NET) return;
  int d = (i < NE) ? ei[NE + i] : (i - NE);
  atomicAdd(&cnt[d], 1);
}

__global__ __launch_bounds__(1024) void k_csr_scan(
    const int* __restrict__ cnt, int* __restrict__ offs,
    float* __restrict__ dinv) {
  __shared__ int sd[1024];
  int tid = threadIdx.x;
  int v = cnt[tid];
  dinv[tid] = rsqrtf((float)v);  // deg >= 1 via self-loops
  sd[tid] = v;
  __syncthreads();
  for (int o = 1; o < 1024; o <<= 1) {
    int t = (tid >= o) ? sd[tid - o] : 0;
    __syncthreads();
    sd[tid] += t;
    __syncthreads();
  }
  if (tid == 0) offs[0] = 0;
  offs[tid + 1] = sd[tid];
}

__global__ void k_csr_fill(const int* __restrict__ ei, const int* __restrict__ offs,
                           int* __restrict__ fillc, const float* __restrict__ dinv,
                           int* __restrict__ asrc, float* __restrict__ anrm) {
  int i = blockIdx.x * 256 + threadIdx.x;
  if (i >= NET) return;
  int s, d;
  if (i < NE) { s = ei[i]; d = ei[NE + i]; }
  else        { s = d = i - NE; }
  int pos = offs[d] + atomicAdd(&fillc[d], 1);
  asrc[pos] = s;
  anrm[pos] = dinv[s] * dinv[d];
}

// ---------------- small fp32 GEMM: C[M,N] = A[M,K] * W[K,N] ----------------
__global__ void k_gemm_f32(const float* __restrict__ A, const float* __restrict__ W,
                           float* __restrict__ C, int M, int K, int N) {
  int n = blockIdx.x * 64 + threadIdx.x;
  int m = blockIdx.y * 4 + threadIdx.y;
  if (n >= N || m >= M) return;
  const float* ar = A + (size_t)m * K;
  float acc = 0.0f;
#pragma unroll 4
  for (int k = 0; k < K; ++k) acc = fmaf(ar[k], W[(size_t)k * N + n], acc);
  C[(size_t)m * N + n] = acc;
}

// ---------------- GCN aggregation (gather over CSR) + bias + leaky ---------
__global__ void k_gcn_agg(const float* __restrict__ h, const int* __restrict__ asrc,
                          const float* __restrict__ anrm, const int* __restrict__ offs,
                          const float* __restrict__ b, float* __restrict__ out,
                          int F) {
  int n = blockIdx.x, f = threadIdx.x;
  if (f >= F) return;
  int e0 = offs[n], e1 = offs[n + 1];
  float acc = 0.0f;
  for (int e = e0; e < e1; ++e)
    acc = fmaf(anrm[e], h[(size_t)asrc[e] * F + f], acc);
  acc += b[f];
  out[(size_t)n * F + f] = acc > 0.0f ? acc : 0.01f * acc;
}

// ---------------- batch norm (train-mode, no affine, biased var) -----------
__global__ void k_bn_stats(const float* __restrict__ x, float* __restrict__ mean,
                           float* __restrict__ rstd, int F) {
  int f = blockIdx.x, tid = threadIdx.x;  // 256 threads
  float s = 0, s2 = 0;
  for (int n = tid; n < 1024; n += 256) {
    float v = x[(size_t)n * F + f];
    s += v;
    s2 += v * v;
  }
#pragma unroll
  for (int m = 1; m < 64; m <<= 1) {
    s += __shfl_xor(s, m, 64);
    s2 += __shfl_xor(s2, m, 64);
  }
  __shared__ float ls[4], ls2[4];
  int wv = tid >> 6;
  if ((tid & 63) == 0) { ls[wv] = s; ls2[wv] = s2; }
  __syncthreads();
  if (tid == 0) {
    float S = ls[0] + ls[1] + ls[2] + ls[3];
    float S2 = ls2[0] + ls2[1] + ls2[2] + ls2[3];
    float mu = S * (1.0f / 1024.0f);
    float var = S2 * (1.0f / 1024.0f) - mu * mu;
    mean[f] = mu;
    rstd[f] = rsqrtf(var + 1e-5f);
  }
}

__global__ void k_bn_apply(float* __restrict__ x, const float* __restrict__ mean,
                           const float* __restrict__ rstd, int F) {
  int f = blockIdx.x * 256 + threadIdx.x;
  int n = blockIdx.y;
  if (f < F) {
    size_t i = (size_t)n * F + f;
    x[i] = (x[i] - mean[f]) * rstd[f];
  }
}

// ---------------- segment_sum + concat + 3x FC -----------------------------
__global__ __launch_bounds__(1024) void k_segfcn(
    const float* __restrict__ x,  // [1024][50]
    const float* __restrict__ gender, const float* __restrict__ handed,
    const float* __restrict__ W1, const float* __restrict__ b1,   // [32][52]
    const float* __restrict__ W2, const float* __restrict__ b2,   // [16][32]
    const float* __restrict__ W3, const float* __restrict__ b3,   // [1][16]
    float* __restrict__ out) {
  __shared__ float seg[16][52];
  __shared__ float y1[16][32];
  __shared__ float y2[16][16];
  int tid = threadIdx.x;
  if (tid < 800) {
    int g = tid / 50, f = tid % 50;
    float s = 0;
    for (int i = 0; i < 64; ++i) s += x[(size_t)(g * 64 + i) * 50 + f];
    seg[g][f] = s;
  }
  if (tid < 16) { seg[tid][50] = gender[tid]; seg[tid][51] = handed[tid]; }
  __syncthreads();
  if (tid < 512) {
    int g = tid >> 5, o = tid & 31;
    float s = b1[o];
    for (int k = 0; k < 52; ++k) s += seg[g][k] * W1[o * 52 + k];
    y1[g][o] = s;
  }
  __syncthreads();
  if (tid < 256) {
    int g = tid >> 4, o = tid & 15;
    float s = b2[o];
    for (int k = 0; k < 32; ++k) s += y1[g][k] * W2[o * 32 + k];
    y2[g][o] = s;
  }
  __syncthreads();
  if (tid < 16) {
    float s = b3[0];
    for (int k = 0; k < 16; ++k) s += y2[tid][k] * W3[k];
    out[tid] = s;
  }
}

// ---------------------------------------------------------------------------
extern "C" void kernel_launch(void* const* d_in, const int* in_sizes, int n_in,
                              void* d_out, int out_size, void* d_ws, size_t ws_size,
                              hipStream_t stream) {
  const float* x_in   = (const float*)d_in[0];
  const int*   ei     = (const int*)d_in[1];
  const float* gender = (const float*)d_in[2];
  const float* handed = (const float*)d_in[3];
  const float* Wih[3] = {(const float*)d_in[4],  (const float*)d_in[8],  (const float*)d_in[12]};
  const float* Whh[3] = {(const float*)d_in[5],  (const float*)d_in[9],  (const float*)d_in[13]};
  const float* bih[3] = {(const float*)d_in[6],  (const float*)d_in[10], (const float*)d_in[14]};
  const float* bhh[3] = {(const float*)d_in[7],  (const float*)d_in[11], (const float*)d_in[15]};
  const float* gW[4]  = {(const float*)d_in[16], (const float*)d_in[18], (const float*)d_in[20], (const float*)d_in[22]};
  const float* gb[4]  = {(const float*)d_in[17], (const float*)d_in[19], (const float*)d_in[21], (const float*)d_in[23]};
  const float* fW[3]  = {(const float*)d_in[24], (const float*)d_in[26], (const float*)d_in[28]};
  const float* fb[3]  = {(const float*)d_in[25], (const float*)d_in[27], (const float*)d_in[29]};
  float* out = (float*)d_out;

  // workspace layout
  char* ws = (char*)d_ws;
  size_t off = 0;
  auto alloc = [&](size_t bytes) -> void* {
    void* p = ws + off;
    off = (off + bytes + 255) & ~(size_t)255;
    return p;
  };
  const int KP0 = 8512;  // 8500 padded to /32
  f16*   X16   = (f16*)alloc((size_t)1024 * KP0 * 2);
  f16*   W016  = (f16*)alloc((size_t)2560 * KP0 * 2);
  f16*   W116  = (f16*)alloc((size_t)2560 * 640 * 2);
  f16*   W216  = (f16*)alloc((size_t)2560 * 640 * 2);
  float* BSUM  = (float*)alloc(3 * 2560 * 4);
  float* XW    = (float*)alloc((size_t)1024 * 2560 * 4);
  float* HS0   = (float*)alloc((size_t)1024 * 640 * 4);
  f16*   HS0H  = (f16*)alloc((size_t)1024 * 640 * 2);
  float* HS1   = (float*)alloc((size_t)1024 * 640 * 4);
  f16*   HS1H  = (f16*)alloc((size_t)1024 * 640 * 2);
  float* HS2   = (float*)alloc((size_t)1024 * 640 * 4);
  f16*   HS2H  = (f16*)alloc((size_t)1024 * 640 * 2);
  float* GA    = (float*)alloc((size_t)1024 * 320 * 4);
  float* GB    = (float*)alloc((size_t)1024 * 320 * 4);
  int*   CNT   = (int*)alloc(1024 * 4);
  int*   OFFS  = (int*)alloc(1025 * 4);
  int*   FILLC = (int*)alloc(1024 * 4);
  float* DINV  = (float*)alloc(1024 * 4);
  int*   ASRC  = (int*)alloc(NET * 4);
  float* ANRM  = (float*)alloc(NET * 4);
  float* MEAN  = (float*)alloc(320 * 4);
  float* RSTD  = (float*)alloc(320 * 4);
  unsigned* SYNC = (unsigned*)alloc(1024);  // 3 sync areas, 64 words apart
  (void)ws_size; (void)in_sizes; (void)n_in; (void)out_size;

  // conversions & bias sums
  k_cvt_pad<<<dim3(34, 1024), 256, 0, stream>>>(x_in, X16, 8500, KP0);
  k_cvt_pad<<<dim3(34, 2560), 256, 0, stream>>>(Wih[0], W016, 8500, KP0);
  k_cvt_pad<<<dim3(3, 2560), 256, 0, stream>>>(Wih[1], W116, 640, 640);
  k_cvt_pad<<<dim3(3, 2560), 256, 0, stream>>>(Wih[2], W216, 640, 640);
  for (int l = 0; l < 3; ++l)
    k_vadd<<<10, 256, 0, stream>>>(bih[l], bhh[l], BSUM + l * 2560, 2560);

  // zero counters (ws is poisoned 0xAA each timed call)
  k_zero<<<5, 256, 0, stream>>>(CNT, 1024);
  k_zero<<<5, 256, 0, stream>>>(FILLC, 1024);
  k_zero<<<1, 256, 0, stream>>>((int*)SYNC, 192);

  // CSR build
  k_csr_count<<<68, 256, 0, stream>>>(ei, CNT);
  k_csr_scan<<<1, 1024, 0, stream>>>(CNT, OFFS, DINV);
  k_csr_fill<<<68, 256, 0, stream>>>(ei, OFFS, FILLC, DINV, ASRC, ANRM);

  // LSTM: layer 0
  k_gemm_bt_f16<<<dim3(20, 8), 256, 0, stream>>>(X16, W016, BSUM, XW, 1024, 2560, KP0);
  k_lstm<<<RB, 512, 0, stream>>>(Whh[0], XW, HS0, HS0H, SYNC);
  // layer 1
  k_gemm_bt_f16<<<dim3(20, 8), 256, 0, stream>>>(HS0H, W116, BSUM + 2560, XW, 1024, 2560, 640);
  k_lstm<<<RB, 512, 0, stream>>>(Whh[1], XW, HS1, HS1H, SYNC + 64);
  // layer 2
  k_gemm_bt_f16<<<dim3(20, 8), 256, 0, stream>>>(HS1H, W216, BSUM + 5120, XW, 1024, 2560, 640);
  k_lstm<<<RB, 512, 0, stream>>>(Whh[2], XW, HS2, HS2H, SYNC + 128);

  // GCN stack
  const float* gin = HS2;
  int Fin = 640;
  const int Fo[4] = {320, 180, 90, 50};
  for (int l = 0; l < 4; ++l) {
    int F = Fo[l];
    k_gemm_f32<<<dim3((F + 63) / 64, 256), dim3(64, 4), 0, stream>>>(gin, gW[l], GA, 1024, Fin, F);
    k_gcn_agg<<<1024, ((F + 63) / 64) * 64, 0, stream>>>(GA, ASRC, ANRM, OFFS, gb[l], GB, F);
    k_bn_stats<<<F, 256, 0, stream>>>(GB, MEAN, RSTD, F);
    k_bn_apply<<<dim3((F + 255) / 256, 1024), 256, 0, stream>>>(GB, MEAN, RSTD, F);
    gin = GB;
    Fin = F;
  }

  // readout
  k_segfcn<<<1, 1024, 0, stream>>>(GB, gender, handed, fW[0], fb[0], fW[1], fb[1], fW[2], fb[2], out);
}

// Round 7
// 3460.982 us; speedup vs baseline: 8.1335x; 2.9303x over previous
//
#include <hip/hip_runtime.h>
#include <cstdint>
#include <cstddef>

// ---------------------------------------------------------------------------
// GCNLSTMRawPluginGenderHanded: full-network forward on MI355X.
//  x_in[1024,8500] --LSTM(3 layers, H=640, seq=nodes)--> [1024,640]
//  --4x(GCNConv -> leaky_relu -> BN)--> [1024,50] --segment_sum(64)-->
//  [16,50] ++ gender,handed --3xFC--> [16,1]
//
// Strategy (evolved over rounds; round-6 measured 3.11us/step, LLC-synced):
//  - layer-0 input projection as f16 MFMA GEMM (m97-structure 128^2 tile)
//  - LSTM: ONE fused kernel, 60 blocks = 3 layer-groups x 20. Tagged
//    self-validating publish: h published as (tag<<16)|f16 single dword via
//    direct-to-LLC (sc0 sc1) stores; consumers poll the data itself (no
//    counter, no separate h load, no drain on critical path). Layers 1/2
//    compute their input projection in-kernel (2nd register matvec), so the
//    3 layers pipeline: 3072 -> 1026 sequential rounds.
//  - GCN aggregation via device-built CSR (gather, no per-feature atomics)
// ---------------------------------------------------------------------------

typedef _Float16 f16;
typedef __attribute__((ext_vector_type(2))) _Float16 f16x2;
typedef __attribute__((ext_vector_type(8))) _Float16 f16x8;
typedef __attribute__((ext_vector_type(4))) float f32x4;

#define DEVFN static __device__ __forceinline__

DEVFN unsigned pkh2(float a, float b) {
  unsigned short lo = __builtin_bit_cast(unsigned short, (_Float16)a);
  unsigned short hi = __builtin_bit_cast(unsigned short, (_Float16)b);
  return ((unsigned)hi << 16) | (unsigned)lo;
}
DEVFN float fdot2u(unsigned a, unsigned b, float c) {
  return __builtin_amdgcn_fdot2(__builtin_bit_cast(f16x2, a),
                                __builtin_bit_cast(f16x2, b), c, false);
}
DEVFN float sigm(float x) { return 1.0f / (1.0f + __expf(-x)); }
DEVFN float tanh_(float x) {
  float a = fabsf(x);
  float e = __expf(-2.0f * a);          // e in (0,1], never overflows
  float t = (1.0f - e) / (1.0f + e);
  return x < 0.0f ? -t : t;
}

// ---- direct-to-LLC helpers (sc0 sc1 = bypass L1 + per-XCD L2) -------------
DEVFN void st_llc_u32(unsigned* p, unsigned v) {
  asm volatile("global_store_dword %0, %1, off sc0 sc1"
               :: "v"(p), "v"(v) : "memory");
}
DEVFN void ld2u_llc(const unsigned* p0, const unsigned* p1,
                    unsigned& a, unsigned& b) {
  asm volatile("global_load_dword %0, %2, off sc0 sc1\n\t"
               "global_load_dword %1, %3, off sc0 sc1\n\t"
               "s_waitcnt vmcnt(0)"
               : "=&v"(a), "=&v"(b) : "v"(p0), "v"(p1) : "memory");
}
DEVFN void ld4u_llc(const unsigned* p0, const unsigned* p1,
                    const unsigned* p2, const unsigned* p3,
                    unsigned& a, unsigned& b, unsigned& c, unsigned& d) {
  asm volatile("global_load_dword %0, %4, off sc0 sc1\n\t"
               "global_load_dword %1, %5, off sc0 sc1\n\t"
               "global_load_dword %2, %6, off sc0 sc1\n\t"
               "global_load_dword %3, %7, off sc0 sc1\n\t"
               "s_waitcnt vmcnt(0)"
               : "=&v"(a), "=&v"(b), "=&v"(c), "=&v"(d)
               : "v"(p0), "v"(p1), "v"(p2), "v"(p3) : "memory");
}

// ---------------- convert fp32 -> f16 with K padding (zeros) ---------------
__global__ void k_cvt_pad(const float* __restrict__ src, f16* __restrict__ dst,
                          int K, int KP) {
  int r = blockIdx.y;
  int k = blockIdx.x * 256 + threadIdx.x;
  if (k >= KP) return;
  float v = (k < K) ? src[(size_t)r * K + k] : 0.0f;
  dst[(size_t)r * KP + k] = (f16)v;
}

__global__ void k_vadd(const float* __restrict__ a, const float* __restrict__ b,
                       float* __restrict__ o, int n) {
  int i = blockIdx.x * 256 + threadIdx.x;
  if (i < n) o[i] = a[i] + b[i];
}

__global__ void k_zero(int* __restrict__ p, int n) {
  int i = blockIdx.x * 256 + threadIdx.x;
  if (i < n) p[i] = 0;
}

// ---------------- f16 MFMA GEMM: C[M,N] = A[M,K] * B[N,K]^T + bias[N] ------
__global__ __launch_bounds__(256, 2) void k_gemm_bt_f16(
    const f16* __restrict__ A, const f16* __restrict__ B,
    const float* __restrict__ bias, float* __restrict__ C,
    int M, int N, int K) {
  __shared__ __align__(16) f16 As[128 * 32];
  __shared__ __align__(16) f16 Bs[128 * 32];
  const int tid = threadIdx.x;
  const int wave = tid >> 6, lane = tid & 63;
  const int l15 = lane & 15, l4 = lane >> 4;
  const int bm = blockIdx.y * 128, bn = blockIdx.x * 128;
  const int wm = (wave >> 1) * 64, wn = (wave & 1) * 64;
  const int srow = tid >> 2;          // staging: row within 64-row half-tile
  const int skk = (tid & 3) * 8;      // staging: k offset (8 f16 = 16B)
  f32x4 acc[4][4] = {};
  for (int k0 = 0; k0 < K; k0 += 32) {
    __syncthreads();  // protect LDS against previous iteration readers
#pragma unroll
    for (int i = 0; i < 2; ++i) {
      const f16* ga = A + (size_t)(bm + i * 64 + srow) * K + (k0 + skk);
      const f16* gb = B + (size_t)(bn + i * 64 + srow) * K + (k0 + skk);
      char* la = (char*)As + i * 4096 + wave * 1024;  // wave-uniform LDS base
      char* lb = (char*)Bs + i * 4096 + wave * 1024;
      __builtin_amdgcn_global_load_lds(
          (const __attribute__((address_space(1))) void*)ga,
          (__attribute__((address_space(3))) void*)la, 16, 0, 0);
      __builtin_amdgcn_global_load_lds(
          (const __attribute__((address_space(1))) void*)gb,
          (__attribute__((address_space(3))) void*)lb, 16, 0, 0);
    }
    __syncthreads();  // drains vmcnt (global_load_lds) + lgkm
    f16x8 af[4], bf[4];
#pragma unroll
    for (int mi = 0; mi < 4; ++mi)
      af[mi] = *(const f16x8*)&As[(wm + mi * 16 + l15) * 32 + l4 * 8];
#pragma unroll
    for (int nj = 0; nj < 4; ++nj)
      bf[nj] = *(const f16x8*)&Bs[(wn + nj * 16 + l15) * 32 + l4 * 8];
#pragma unroll
    for (int mi = 0; mi < 4; ++mi)
#pragma unroll
      for (int nj = 0; nj < 4; ++nj)
        acc[mi][nj] = __builtin_amdgcn_mfma_f32_16x16x32_f16(
            af[mi], bf[nj], acc[mi][nj], 0, 0, 0);
  }
#pragma unroll
  for (int mi = 0; mi < 4; ++mi) {
#pragma unroll
    for (int nj = 0; nj < 4; ++nj) {
      int row = bm + wm + mi * 16 + l4 * 4;
      int col = bn + wn + nj * 16 + l15;
      float bv = bias[col];
#pragma unroll
      for (int j = 0; j < 4; ++j)
        C[(size_t)(row + j) * N + col] = acc[mi][nj][j] + bv;
    }
  }
}

// ---------------- fused 3-layer pipelined LSTM (tagged LLC sync) -----------
// 60 blocks x 512 threads: block b -> layer = b/20, role = b%20.
// Role r owns h-dims [r*32, r*32+32) (128 gate rows). Thread t: slice=t&15
// (40 cols), rowg=t>>4 (one h-dim). Weights register-resident packed f16:
// wh[4][20] (Whh) + wi[4][20] (Wih, layers 1/2). Per step:
//   poll tagged dwords (single ld4+wait): own h_{t-1} (tag t) and, for
//   layers 1/2, prev-layer h_t (tag t+1); stage to double-buffered LDS;
//   one barrier; dot2 matvec(s); 16-lane shfl reduce; gates; publish
//   (tag t+1)<<16|f16(h) fire-and-forget. Layer l runs 1 round behind l-1
//   => 1026 sequential rounds total. Spins bounded (sticky dead-flag).
#define RB 20
#define SPIN_CAP 300000
__global__ __launch_bounds__(512, 2) void k_lstm3(
    const float* __restrict__ Whh0, const float* __restrict__ Whh1,
    const float* __restrict__ Whh2,          // [2560][640] fp32 each
    const f16* __restrict__ Wih1, const f16* __restrict__ Wih2,  // [2560][640]
    const float* __restrict__ xw0,   // [1024][2560]: x@Wih0^T + bih0 + bhh0
    const float* __restrict__ bsum,  // [3][2560] (rows 1,2 used here)
    unsigned* __restrict__ tag0, unsigned* __restrict__ tag1,
    unsigned* __restrict__ tag2,     // [1024][640] tagged f16 h per layer
    float* __restrict__ hs2) {       // [1024][640] fp32 layer-2 out (GCN in)
  __shared__ unsigned ho2s[2][320];  // own-layer h_{t-1}, packed half2
  __shared__ unsigned hp2s[2][320];  // prev-layer h_t, packed half2
  const int tid = threadIdx.x;
  const int layer = blockIdx.x / RB;
  const int role = blockIdx.x % RB;
  const int slice = tid & 15;
  const int rowg = tid >> 4;                 // 0..31
  const int dim = role * 32 + rowg;          // owned h-dim
  const int c0 = slice * 40;

  const float* Whh = (layer == 0) ? Whh0 : (layer == 1) ? Whh1 : Whh2;
  const f16* Wih = (layer == 2) ? Wih2 : Wih1;                // layer0: unused
  unsigned* tago = (layer == 0) ? tag0 : (layer == 1) ? tag1 : tag2;
  const unsigned* tagp = (layer == 2) ? tag1 : tag0;          // layer0: unused

  unsigned wh[4][20];
#pragma unroll
  for (int g = 0; g < 4; ++g) {
    const float* wr = Whh + (size_t)(g * 640 + dim) * 640 + c0;
#pragma unroll
    for (int c = 0; c < 20; ++c) {
      float2 f = *(const float2*)(wr + 2 * c);
      wh[g][c] = pkh2(f.x, f.y);
    }
  }
  unsigned wi[4][20];
  if (layer > 0) {
#pragma unroll
    for (int g = 0; g < 4; ++g) {
      const unsigned* wr = (const unsigned*)(Wih + (size_t)(g * 640 + dim) * 640 + c0);
#pragma unroll
      for (int c = 0; c < 20; ++c) wi[g][c] = wr[c];
    }
  } else {
#pragma unroll
    for (int g = 0; g < 4; ++g)
#pragma unroll
      for (int c = 0; c < 20; ++c) wi[g][c] = 0u;
  }
  const bool isred = (slice == 0);
  float b0 = 0, b1 = 0, b2 = 0, b3 = 0;
  if (isred && layer > 0) {
    const float* br = bsum + layer * 2560 + dim;
    b0 = br[0]; b1 = br[640]; b2 = br[1280]; b3 = br[1920];
  }
  float creg = 0.0f;
  int dead = 0;
  for (int t = 0; t < 1024; ++t) {
    const int par = t & 1;
    float xwv0 = b0, xwv1 = b1, xwv2 = b2, xwv3 = b3;
    if (isred && layer == 0) {
      const float* xr = xw0 + (size_t)t * 2560 + dim;
      xwv0 = xr[0]; xwv1 = xr[640]; xwv2 = xr[1280]; xwv3 = xr[1920];
    }
    if (tid < 320) {
      const unsigned tgo = (unsigned)t;        // own h_{t-1} carries tag t
      const unsigned tgp = (unsigned)(t + 1);  // prev-layer h_t carries tag t+1
      const bool needo = (t > 0), needp = (layer > 0);
      unsigned v0 = 0, v1 = 0, v2 = 0, v3 = 0;
      if (!dead) {
        if (needo && needp) {
          const unsigned* po = tago + (size_t)(t - 1) * 640 + 2 * tid;
          const unsigned* pp = tagp + (size_t)t * 640 + 2 * tid;
          int spins = 0;
          for (;;) {
            ld4u_llc(po, po + 1, pp, pp + 1, v0, v1, v2, v3);
            if ((v0 >> 16) == tgo && (v1 >> 16) == tgo &&
                (v2 >> 16) == tgp && (v3 >> 16) == tgp) break;
            if (++spins > SPIN_CAP) { dead = 1; break; }
          }
        } else if (needo) {
          const unsigned* po = tago + (size_t)(t - 1) * 640 + 2 * tid;
          int spins = 0;
          for (;;) {
            ld2u_llc(po, po + 1, v0, v1);
            if ((v0 >> 16) == tgo && (v1 >> 16) == tgo) break;
            if (++spins > SPIN_CAP) { dead = 1; break; }
          }
        } else if (needp) {
          const unsigned* pp = tagp + (size_t)t * 640 + 2 * tid;
          int spins = 0;
          for (;;) {
            ld2u_llc(pp, pp + 1, v2, v3);
            if ((v2 >> 16) == tgp && (v3 >> 16) == tgp) break;
            if (++spins > SPIN_CAP) { dead = 1; break; }
          }
        }
      }
      ho2s[par][tid] = needo ? ((v0 & 0xffffu) | (v1 << 16)) : 0u;
      hp2s[par][tid] = (v2 & 0xffffu) | (v3 << 16);
    }
    __syncthreads();  // LDS staged; double-buffer removes the end barrier
    float a0 = 0, a1 = 0, a2 = 0, a3 = 0;
#pragma unroll
    for (int c = 0; c < 20; ++c) {
      unsigned hv = ho2s[par][slice * 20 + c];
      a0 = fdot2u(wh[0][c], hv, a0);
      a1 = fdot2u(wh[1][c], hv, a1);
      a2 = fdot2u(wh[2][c], hv, a2);
      a3 = fdot2u(wh[3][c], hv, a3);
    }
    if (layer > 0) {
#pragma unroll
      for (int c = 0; c < 20; ++c) {
        unsigned hv = hp2s[par][slice * 20 + c];
        a0 = fdot2u(wi[0][c], hv, a0);
        a1 = fdot2u(wi[1][c], hv, a1);
        a2 = fdot2u(wi[2][c], hv, a2);
        a3 = fdot2u(wi[3][c], hv, a3);
      }
    }
#pragma unroll
    for (int m = 1; m < 16; m <<= 1) {
      a0 += __shfl_xor(a0, m, 64);
      a1 += __shfl_xor(a1, m, 64);
      a2 += __shfl_xor(a2, m, 64);
      a3 += __shfl_xor(a3, m, 64);
    }
    if (isred) {
      float gi = sigm(xwv0 + a0);
      float gf = sigm(xwv1 + a1);
      float gg = tanh_(xwv2 + a2);
      float go = sigm(xwv3 + a3);
      creg = gf * creg + gi * gg;
      float h = go * tanh_(creg);
      unsigned hb = (unsigned)__builtin_bit_cast(unsigned short, (_Float16)h);
      st_llc_u32(tago + (size_t)t * 640 + dim, ((unsigned)(t + 1) << 16) | hb);
      if (layer == 2) hs2[(size_t)t * 640 + dim] = h;  // plain store for GCN
    }
    // no end barrier: double-buffered LDS + next step's __syncthreads suffice
  }
}

// ---------------- CSR build (edges + self-loops), degrees ------------------
#define NE 16384
#define NN 1024
#define NET (NE + NN)

__global__ void k_csr_count(const int* __restrict__ ei, int* __restrict__ cnt) {
  int i = blockIdx.x * 256 + threadIdx.x;
  if (i >= NET) return;
  int d = (i < NE) ? ei[NE + i] : (i - NE);
  atomicAdd(&cnt[d], 1);
}

__global__ __launch_bounds__(1024) void k_csr_scan(
    const int* __restrict__ cnt, int* __restrict__ offs,
    float* __restrict__ dinv) {
  __shared__ int sd[1024];
  int tid = threadIdx.x;
  int v = cnt[tid];
  dinv[tid] = rsqrtf((float)v);  // deg >= 1 via self-loops
  sd[tid] = v;
  __syncthreads();
  for (int o = 1; o < 1024; o <<= 1) {
    int t = (tid >= o) ? sd[tid - o] : 0;
    __syncthreads();
    sd[tid] += t;
    __syncthreads();
  }
  if (tid == 0) offs[0] = 0;
  offs[tid + 1] = sd[tid];
}

__global__ void k_csr_fill(const int* __restrict__ ei, const int* __restrict__ offs,
                           int* __restrict__ fillc, const float* __restrict__ dinv,
                           int* __restrict__ asrc, float* __restrict__ anrm) {
  int i = blockIdx.x * 256 + threadIdx.x;
  if (i >= NET) return;
  int s, d;
  if (i < NE) { s = ei[i]; d = ei[NE + i]; }
  else        { s = d = i - NE; }
  int pos = offs[d] + atomicAdd(&fillc[d], 1);
  asrc[pos] = s;
  anrm[pos] = dinv[s] * dinv[d];
}

// ---------------- small fp32 GEMM: C[M,N] = A[M,K] * W[K,N] ----------------
__global__ void k_gemm_f32(const float* __restrict__ A, const float* __restrict__ W,
                           float* __restrict__ C, int M, int K, int N) {
  int n = blockIdx.x * 64 + threadIdx.x;
  int m = blockIdx.y * 4 + threadIdx.y;
  if (n >= N || m >= M) return;
  const float* ar = A + (size_t)m * K;
  float acc = 0.0f;
#pragma unroll 4
  for (int k = 0; k < K; ++k) acc = fmaf(ar[k], W[(size_t)k * N + n], acc);
  C[(size_t)m * N + n] = acc;
}

// ---------------- GCN aggregation (gather over CSR) + bias + leaky ---------
__global__ void k_gcn_agg(const float* __restrict__ h, const int* __restrict__ asrc,
                          const float* __restrict__ anrm, const int* __restrict__ offs,
                          const float* __restrict__ b, float* __restrict__ out,
                          int F) {
  int n = blockIdx.x, f = threadIdx.x;
  if (f >= F) return;
  int e0 = offs[n], e1 = offs[n + 1];
  float acc = 0.0f;
  for (int e = e0; e < e1; ++e)
    acc = fmaf(anrm[e], h[(size_t)asrc[e] * F + f], acc);
  acc += b[f];
  out[(size_t)n * F + f] = acc > 0.0f ? acc : 0.01f * acc;
}

// ---------------- batch norm (train-mode, no affine, biased var) -----------
__global__ void k_bn_stats(const float* __restrict__ x, float* __restrict__ mean,
                           float* __restrict__ rstd, int F) {
  int f = blockIdx.x, tid = threadIdx.x;  // 256 threads
  float s = 0, s2 = 0;
  for (int n = tid; n < 1024; n += 256) {
    float v = x[(size_t)n * F + f];
    s += v;
    s2 += v * v;
  }
#pragma unroll
  for (int m = 1; m < 64; m <<= 1) {
    s += __shfl_xor(s, m, 64);
    s2 += __shfl_xor(s2, m, 64);
  }
  __shared__ float ls[4], ls2[4];
  int wv = tid >> 6;
  if ((tid & 63) == 0) { ls[wv] = s; ls2[wv] = s2; }
  __syncthreads();
  if (tid == 0) {
    float S = ls[0] + ls[1] + ls[2] + ls[3];
    float S2 = ls2[0] + ls2[1] + ls2[2] + ls2[3];
    float mu = S * (1.0f / 1024.0f);
    float var = S2 * (1.0f / 1024.0f) - mu * mu;
    mean[f] = mu;
    rstd[f] = rsqrtf(var + 1e-5f);
  }
}

__global__ void k_bn_apply(float* __restrict__ x, const float* __restrict__ mean,
                           const float* __restrict__ rstd, int F) {
  int f = blockIdx.x * 256 + threadIdx.x;
  int n = blockIdx.y;
  if (f < F) {
    size_t i = (size_t)n * F + f;
    x[i] = (x[i] - mean[f]) * rstd[f];
  }
}

// ---------------- segment_sum + concat + 3x FC -----------------------------
__global__ __launch_bounds__(1024) void k_segfcn(
    const float* __restrict__ x,  // [1024][50]
    const float* __restrict__ gender, const float* __restrict__ handed,
    const float* __restrict__ W1, const float* __restrict__ b1,   // [32][52]
    const float* __restrict__ W2, const float* __restrict__ b2,   // [16][32]
    const float* __restrict__ W3, const float* __restrict__ b3,   // [1][16]
    float* __restrict__ out) {
  __shared__ float seg[16][52];
  __shared__ float y1[16][32];
  __shared__ float y2[16][16];
  int tid = threadIdx.x;
  if (tid < 800) {
    int g = tid / 50, f = tid % 50;
    float s = 0;
    for (int i = 0; i < 64; ++i) s += x[(size_t)(g * 64 + i) * 50 + f];
    seg[g][f] = s;
  }
  if (tid < 16) { seg[tid][50] = gender[tid]; seg[tid][51] = handed[tid]; }
  __syncthreads();
  if (tid < 512) {
    int g = tid >> 5, o = tid & 31;
    float s = b1[o];
    for (int k = 0; k < 52; ++k) s += seg[g][k] * W1[o * 52 + k];
    y1[g][o] = s;
  }
  __syncthreads();
  if (tid < 256) {
    int g = tid >> 4, o = tid & 15;
    float s = b2[o];
    for (int k = 0; k < 32; ++k) s += y1[g][k] * W2[o * 32 + k];
    y2[g][o] = s;
  }
  __syncthreads();
  if (tid < 16) {
    float s = b3[0];
    for (int k = 0; k < 16; ++k) s += y2[tid][k] * W3[k];
    out[tid] = s;
  }
}

// ---------------------------------------------------------------------------
extern "C" void kernel_launch(void* const* d_in, const int* in_sizes, int n_in,
                              void* d_out, int out_size, void* d_ws, size_t ws_size,
                              hipStream_t stream) {
  const float* x_in   = (const float*)d_in[0];
  const int*   ei     = (const int*)d_in[1];
  const float* gender = (const float*)d_in[2];
  const float* handed = (const float*)d_in[3];
  const float* Wih[3] = {(const float*)d_in[4],  (const float*)d_in[8],  (const float*)d_in[12]};
  const float* Whh[3] = {(const float*)d_in[5],  (const float*)d_in[9],  (const float*)d_in[13]};
  const float* bih[3] = {(const float*)d_in[6],  (const float*)d_in[10], (const float*)d_in[14]};
  const float* bhh[3] = {(const float*)d_in[7],  (const float*)d_in[11], (const float*)d_in[15]};
  const float* gW[4]  = {(const float*)d_in[16], (const float*)d_in[18], (const float*)d_in[20], (const float*)d_in[22]};
  const float* gb[4]  = {(const float*)d_in[17], (const float*)d_in[19], (const float*)d_in[21], (const float*)d_in[23]};
  const float* fW[3]  = {(const float*)d_in[24], (const float*)d_in[26], (const float*)d_in[28]};
  const float* fb[3]  = {(const float*)d_in[25], (const float*)d_in[27], (const float*)d_in[29]};
  float* out = (float*)d_out;

  // workspace layout
  char* ws = (char*)d_ws;
  size_t off = 0;
  auto alloc = [&](size_t bytes) -> void* {
    void* p = ws + off;
    off = (off + bytes + 255) & ~(size_t)255;
    return p;
  };
  const int KP0 = 8512;  // 8500 padded to /32
  f16*   X16   = (f16*)alloc((size_t)1024 * KP0 * 2);
  f16*   W016  = (f16*)alloc((size_t)2560 * KP0 * 2);
  f16*   W116  = (f16*)alloc((size_t)2560 * 640 * 2);
  f16*   W216  = (f16*)alloc((size_t)2560 * 640 * 2);
  float* BSUM  = (float*)alloc(3 * 2560 * 4);
  float* XW    = (float*)alloc((size_t)1024 * 2560 * 4);
  unsigned* TAGA = (unsigned*)alloc((size_t)3 * 1024 * 640 * 4);  // 3 tag bufs
  float* HS2   = (float*)alloc((size_t)1024 * 640 * 4);
  float* GA    = (float*)alloc((size_t)1024 * 320 * 4);
  float* GB    = (float*)alloc((size_t)1024 * 320 * 4);
  int*   CNT   = (int*)alloc(1024 * 4);
  int*   OFFS  = (int*)alloc(1025 * 4);
  int*   FILLC = (int*)alloc(1024 * 4);
  float* DINV  = (float*)alloc(1024 * 4);
  int*   ASRC  = (int*)alloc(NET * 4);
  float* ANRM  = (float*)alloc(NET * 4);
  float* MEAN  = (float*)alloc(320 * 4);
  float* RSTD  = (float*)alloc(320 * 4);
  unsigned* TAG0 = TAGA;
  unsigned* TAG1 = TAGA + (size_t)1024 * 640;
  unsigned* TAG2 = TAGA + (size_t)2 * 1024 * 640;
  (void)ws_size; (void)in_sizes; (void)n_in; (void)out_size;

  // conversions & bias sums
  k_cvt_pad<<<dim3(34, 1024), 256, 0, stream>>>(x_in, X16, 8500, KP0);
  k_cvt_pad<<<dim3(34, 2560), 256, 0, stream>>>(Wih[0], W016, 8500, KP0);
  k_cvt_pad<<<dim3(3, 2560), 256, 0, stream>>>(Wih[1], W116, 640, 640);
  k_cvt_pad<<<dim3(3, 2560), 256, 0, stream>>>(Wih[2], W216, 640, 640);
  for (int l = 0; l < 3; ++l)
    k_vadd<<<10, 256, 0, stream>>>(bih[l], bhh[l], BSUM + l * 2560, 2560);

  // zero CSR counters and tag buffers (ws poisoned 0xAA each timed call;
  // tag 0 never matches expected tags 1..1024)
  k_zero<<<5, 256, 0, stream>>>(CNT, 1024);
  k_zero<<<5, 256, 0, stream>>>(FILLC, 1024);
  k_zero<<<7680, 256, 0, stream>>>((int*)TAGA, 3 * 1024 * 640);

  // CSR build
  k_csr_count<<<68, 256, 0, stream>>>(ei, CNT);
  k_csr_scan<<<1, 1024, 0, stream>>>(CNT, OFFS, DINV);
  k_csr_fill<<<68, 256, 0, stream>>>(ei, OFFS, FILLC, DINV, ASRC, ANRM);

  // layer-0 input projection (K=8512 f16 MFMA GEMM), then fused 3-layer LSTM
  k_gemm_bt_f16<<<dim3(20, 8), 256, 0, stream>>>(X16, W016, BSUM, XW, 1024, 2560, KP0);
  k_lstm3<<<60, 512, 0, stream>>>(Whh[0], Whh[1], Whh[2],
                                  W116, W216, XW, BSUM,
                                  TAG0, TAG1, TAG2, HS2);

  // GCN stack
  const float* gin = HS2;
  int Fin = 640;
  const int Fo[4] = {320, 180, 90, 50};
  for (int l = 0; l < 4; ++l) {
    int F = Fo[l];
    k_gemm_f32<<<dim3((F + 63) / 64, 256), dim3(64, 4), 0, stream>>>(gin, gW[l], GA, 1024, Fin, F);
    k_gcn_agg<<<1024, ((F + 63) / 64) * 64, 0, stream>>>(GA, ASRC, ANRM, OFFS, gb[l], GB, F);
    k_bn_stats<<<F, 256, 0, stream>>>(GB, MEAN, RSTD, F);
    k_bn_apply<<<dim3((F + 255) / 256, 1024), 256, 0, stream>>>(GB, MEAN, RSTD, F);
    gin = GB;
    Fin = F;
  }

  // readout
  k_segfcn<<<1, 1024, 0, stream>>>(GB, gender, handed, fW[0], fb[0], fW[1], fb[1], fW[2], fb[2], out);
}

// Round 8
// 3228.573 us; speedup vs baseline: 8.7190x; 1.0720x over previous
//
#include <hip/hip_runtime.h>
#include <cstdint>
#include <cstddef>

// ---------------------------------------------------------------------------
// GCNLSTMRawPluginGenderHanded: full-network forward on MI355X.
//  x_in[1024,8500] --LSTM(3 layers, H=640, seq=nodes)--> [1024,640]
//  --4x(GCNConv -> leaky_relu -> BN)--> [1024,50] --segment_sum(64)-->
//  [16,50] ++ gender,handed --3xFC--> [16,1]
//
// Strategy (r7: 3.46ms total, k_lstm3 2.83ms = 2.75us/round):
//  - layer-0 input projection as f16 MFMA GEMM (m97-structure 128^2 tile)
//  - LSTM: ONE fused kernel, 120 blocks = 3 layers x 40 roles (16 dims each).
//    Tagged self-validating publish: h as (tag<<16)|f16 dword via LLC
//    (sc0 sc1); consumers poll the data itself. Layers 1/2 compute their
//    input projection in-kernel -> 1026 sequential rounds.
//    r8: launch_bounds(512,1) so weights are truly register-resident (r7's
//    (512,2) cap forced AGPR ping-pong: VGPR_Count=128 < 160 needed);
//    40 roles/layer halves per-CU dot2 issue.
//  - GCN: BN-apply fused into next GEMM / segfcn (removes 4 dispatches)
// ---------------------------------------------------------------------------

typedef _Float16 f16;
typedef __attribute__((ext_vector_type(2))) _Float16 f16x2;
typedef __attribute__((ext_vector_type(8))) _Float16 f16x8;
typedef __attribute__((ext_vector_type(4))) float f32x4;

#define DEVFN static __device__ __forceinline__

DEVFN unsigned pkh2(float a, float b) {
  unsigned short lo = __builtin_bit_cast(unsigned short, (_Float16)a);
  unsigned short hi = __builtin_bit_cast(unsigned short, (_Float16)b);
  return ((unsigned)hi << 16) | (unsigned)lo;
}
DEVFN float fdot2u(unsigned a, unsigned b, float c) {
  return __builtin_amdgcn_fdot2(__builtin_bit_cast(f16x2, a),
                                __builtin_bit_cast(f16x2, b), c, false);
}
DEVFN float sigm(float x) { return 1.0f / (1.0f + __expf(-x)); }
DEVFN float tanh_(float x) {
  float a = fabsf(x);
  float e = __expf(-2.0f * a);          // e in (0,1], never overflows
  float t = (1.0f - e) / (1.0f + e);
  return x < 0.0f ? -t : t;
}

// ---- direct-to-LLC helpers (sc0 sc1 = bypass L1 + per-XCD L2) -------------
DEVFN void st_llc_u32(unsigned* p, unsigned v) {
  asm volatile("global_store_dword %0, %1, off sc0 sc1"
               :: "v"(p), "v"(v) : "memory");
}
DEVFN void ld2u_llc(const unsigned* p0, const unsigned* p1,
                    unsigned& a, unsigned& b) {
  asm volatile("global_load_dword %0, %2, off sc0 sc1\n\t"
               "global_load_dword %1, %3, off sc0 sc1\n\t"
               "s_waitcnt vmcnt(0)"
               : "=&v"(a), "=&v"(b) : "v"(p0), "v"(p1) : "memory");
}
DEVFN void ld4u_llc(const unsigned* p0, const unsigned* p1,
                    const unsigned* p2, const unsigned* p3,
                    unsigned& a, unsigned& b, unsigned& c, unsigned& d) {
  asm volatile("global_load_dword %0, %4, off sc0 sc1\n\t"
               "global_load_dword %1, %5, off sc0 sc1\n\t"
               "global_load_dword %2, %6, off sc0 sc1\n\t"
               "global_load_dword %3, %7, off sc0 sc1\n\t"
               "s_waitcnt vmcnt(0)"
               : "=&v"(a), "=&v"(b), "=&v"(c), "=&v"(d)
               : "v"(p0), "v"(p1), "v"(p2), "v"(p3) : "memory");
}

// ---------------- convert fp32 -> f16 with K padding (zeros) ---------------
__global__ void k_cvt_pad(const float* __restrict__ src, f16* __restrict__ dst,
                          int K, int KP) {
  int r = blockIdx.y;
  int k = blockIdx.x * 256 + threadIdx.x;
  if (k >= KP) return;
  float v = (k < K) ? src[(size_t)r * K + k] : 0.0f;
  dst[(size_t)r * KP + k] = (f16)v;
}

__global__ void k_vadd(const float* __restrict__ a, const float* __restrict__ b,
                       float* __restrict__ o, int n) {
  int i = blockIdx.x * 256 + threadIdx.x;
  if (i < n) o[i] = a[i] + b[i];
}

__global__ void k_zero(int* __restrict__ p, int n) {
  int i = blockIdx.x * 256 + threadIdx.x;
  if (i < n) p[i] = 0;
}

// ---------------- f16 MFMA GEMM: C[M,N] = A[M,K] * B[N,K]^T + bias[N] ------
__global__ __launch_bounds__(256, 2) void k_gemm_bt_f16(
    const f16* __restrict__ A, const f16* __restrict__ B,
    const float* __restrict__ bias, float* __restrict__ C,
    int M, int N, int K) {
  __shared__ __align__(16) f16 As[128 * 32];
  __shared__ __align__(16) f16 Bs[128 * 32];
  const int tid = threadIdx.x;
  const int wave = tid >> 6, lane = tid & 63;
  const int l15 = lane & 15, l4 = lane >> 4;
  const int bm = blockIdx.y * 128, bn = blockIdx.x * 128;
  const int wm = (wave >> 1) * 64, wn = (wave & 1) * 64;
  const int srow = tid >> 2;          // staging: row within 64-row half-tile
  const int skk = (tid & 3) * 8;      // staging: k offset (8 f16 = 16B)
  f32x4 acc[4][4] = {};
  for (int k0 = 0; k0 < K; k0 += 32) {
    __syncthreads();  // protect LDS against previous iteration readers
#pragma unroll
    for (int i = 0; i < 2; ++i) {
      const f16* ga = A + (size_t)(bm + i * 64 + srow) * K + (k0 + skk);
      const f16* gb = B + (size_t)(bn + i * 64 + srow) * K + (k0 + skk);
      char* la = (char*)As + i * 4096 + wave * 1024;  // wave-uniform LDS base
      char* lb = (char*)Bs + i * 4096 + wave * 1024;
      __builtin_amdgcn_global_load_lds(
          (const __attribute__((address_space(1))) void*)ga,
          (__attribute__((address_space(3))) void*)la, 16, 0, 0);
      __builtin_amdgcn_global_load_lds(
          (const __attribute__((address_space(1))) void*)gb,
          (__attribute__((address_space(3))) void*)lb, 16, 0, 0);
    }
    __syncthreads();  // drains vmcnt (global_load_lds) + lgkm
    f16x8 af[4], bf[4];
#pragma unroll
    for (int mi = 0; mi < 4; ++mi)
      af[mi] = *(const f16x8*)&As[(wm + mi * 16 + l15) * 32 + l4 * 8];
#pragma unroll
    for (int nj = 0; nj < 4; ++nj)
      bf[nj] = *(const f16x8*)&Bs[(wn + nj * 16 + l15) * 32 + l4 * 8];
#pragma unroll
    for (int mi = 0; mi < 4; ++mi)
#pragma unroll
      for (int nj = 0; nj < 4; ++nj)
        acc[mi][nj] = __builtin_amdgcn_mfma_f32_16x16x32_f16(
            af[mi], bf[nj], acc[mi][nj], 0, 0, 0);
  }
#pragma unroll
  for (int mi = 0; mi < 4; ++mi) {
#pragma unroll
    for (int nj = 0; nj < 4; ++nj) {
      int row = bm + wm + mi * 16 + l4 * 4;
      int col = bn + wn + nj * 16 + l15;
      float bv = bias[col];
#pragma unroll
      for (int j = 0; j < 4; ++j)
        C[(size_t)(row + j) * N + col] = acc[mi][nj][j] + bv;
    }
  }
}

// ---------------- fused 3-layer pipelined LSTM (tagged LLC sync) -----------
// 120 blocks x 512 threads: block b -> layer = b/40, role = b%40.
// Role r owns h-dims [r*16, r*16+16). Thread t: slice = t&31 (20 cols),
// rowg = t>>5 (one h-dim). Weights register-resident packed f16:
// wh[4][10] (Whh) + wi[4][10] (Wih, layers 1/2) = 80 VGPRs.
// Per step: poll tagged dwords (tid<320: own h_{t-1} tag t; layers 1/2 also
// prev-layer h_t tag t+1); stage to double-buffered LDS; one barrier; dot2
// matvec; 32-lane shfl reduce; gates; publish (t+1)<<16|f16(h) fire&forget.
// Layer l runs 1 round behind l-1 => 1026 sequential rounds. Spins bounded.
#define RPL 40
#define SPIN_CAP 300000
__global__ __launch_bounds__(512, 1) void k_lstm3(
    const float* __restrict__ Whh0, const float* __restrict__ Whh1,
    const float* __restrict__ Whh2,          // [2560][640] fp32 each
    const f16* __restrict__ Wih1, const f16* __restrict__ Wih2,  // [2560][640]
    const float* __restrict__ xw0,   // [1024][2560]: x@Wih0^T + bih0 + bhh0
    const float* __restrict__ bsum,  // [3][2560] (rows 1,2 used here)
    unsigned* __restrict__ tag0, unsigned* __restrict__ tag1,
    unsigned* __restrict__ tag2,     // [1024][640] tagged f16 h per layer
    float* __restrict__ hs2) {       // [1024][640] fp32 layer-2 out (GCN in)
  __shared__ unsigned ho2s[2][320];  // own-layer h_{t-1}, packed half2
  __shared__ unsigned hp2s[2][320];  // prev-layer h_t, packed half2
  const int tid = threadIdx.x;
  const int layer = blockIdx.x / RPL;
  const int role = blockIdx.x % RPL;
  const int slice = tid & 31;                // 0..31, 20 cols each
  const int rowg = tid >> 5;                 // 0..15
  const int dim = role * 16 + rowg;          // owned h-dim
  const int c0 = slice * 20;

  const float* Whh = (layer == 0) ? Whh0 : (layer == 1) ? Whh1 : Whh2;
  const f16* Wih = (layer == 2) ? Wih2 : Wih1;                // layer0: unused
  unsigned* tago = (layer == 0) ? tag0 : (layer == 1) ? tag1 : tag2;
  const unsigned* tagp = (layer == 2) ? tag1 : tag0;          // layer0: unused

  unsigned wh[4][10];
#pragma unroll
  for (int g = 0; g < 4; ++g) {
    const float* wr = Whh + (size_t)(g * 640 + dim) * 640 + c0;
#pragma unroll
    for (int c = 0; c < 10; ++c) {
      float2 f = *(const float2*)(wr + 2 * c);
      wh[g][c] = pkh2(f.x, f.y);
    }
  }
  unsigned wi[4][10];
  if (layer > 0) {
#pragma unroll
    for (int g = 0; g < 4; ++g) {
      const unsigned* wr = (const unsigned*)(Wih + (size_t)(g * 640 + dim) * 640 + c0);
#pragma unroll
      for (int c = 0; c < 10; ++c) wi[g][c] = wr[c];
    }
  } else {
#pragma unroll
    for (int g = 0; g < 4; ++g)
#pragma unroll
      for (int c = 0; c < 10; ++c) wi[g][c] = 0u;
  }
  const bool isred = (slice == 0);
  float b0 = 0, b1 = 0, b2 = 0, b3 = 0;
  if (isred && layer > 0) {
    const float* br = bsum + layer * 2560 + dim;
    b0 = br[0]; b1 = br[640]; b2 = br[1280]; b3 = br[1920];
  }
  float creg = 0.0f;
  int dead = 0;
  for (int t = 0; t < 1024; ++t) {
    const int par = t & 1;
    float xwv0 = b0, xwv1 = b1, xwv2 = b2, xwv3 = b3;
    if (isred && layer == 0) {
      const float* xr = xw0 + (size_t)t * 2560 + dim;
      xwv0 = xr[0]; xwv1 = xr[640]; xwv2 = xr[1280]; xwv3 = xr[1920];
    }
    if (tid < 320) {
      const unsigned tgo = (unsigned)t;        // own h_{t-1} carries tag t
      const unsigned tgp = (unsigned)(t + 1);  // prev-layer h_t carries tag t+1
      const bool needo = (t > 0), needp = (layer > 0);
      unsigned v0 = 0, v1 = 0, v2 = 0, v3 = 0;
      if (!dead) {
        if (needo && needp) {
          const unsigned* po = tago + (size_t)(t - 1) * 640 + 2 * tid;
          const unsigned* pp = tagp + (size_t)t * 640 + 2 * tid;
          int spins = 0;
          for (;;) {
            ld4u_llc(po, po + 1, pp, pp + 1, v0, v1, v2, v3);
            if ((v0 >> 16) == tgo && (v1 >> 16) == tgo &&
                (v2 >> 16) == tgp && (v3 >> 16) == tgp) break;
            if (++spins > SPIN_CAP) { dead = 1; break; }
          }
        } else if (needo) {
          const unsigned* po = tago + (size_t)(t - 1) * 640 + 2 * tid;
          int spins = 0;
          for (;;) {
            ld2u_llc(po, po + 1, v0, v1);
            if ((v0 >> 16) == tgo && (v1 >> 16) == tgo) break;
            if (++spins > SPIN_CAP) { dead = 1; break; }
          }
        } else if (needp) {
          const unsigned* pp = tagp + (size_t)t * 640 + 2 * tid;
          int spins = 0;
          for (;;) {
            ld2u_llc(pp, pp + 1, v2, v3);
            if ((v2 >> 16) == tgp && (v3 >> 16) == tgp) break;
            if (++spins > SPIN_CAP) { dead = 1; break; }
          }
        }
      }
      ho2s[par][tid] = needo ? ((v0 & 0xffffu) | (v1 << 16)) : 0u;
      hp2s[par][tid] = (v2 & 0xffffu) | (v3 << 16);
    }
    __syncthreads();  // LDS staged; double-buffer removes the end barrier
    float a0 = 0, a1 = 0, a2 = 0, a3 = 0;
#pragma unroll
    for (int c = 0; c < 10; ++c) {
      unsigned hv = ho2s[par][slice * 10 + c];
      a0 = fdot2u(wh[0][c], hv, a0);
      a1 = fdot2u(wh[1][c], hv, a1);
      a2 = fdot2u(wh[2][c], hv, a2);
      a3 = fdot2u(wh[3][c], hv, a3);
    }
    if (layer > 0) {
#pragma unroll
      for (int c = 0; c < 10; ++c) {
        unsigned hv = hp2s[par][slice * 10 + c];
        a0 = fdot2u(wi[0][c], hv, a0);
        a1 = fdot2u(wi[1][c], hv, a1);
        a2 = fdot2u(wi[2][c], hv, a2);
        a3 = fdot2u(wi[3][c], hv, a3);
      }
    }
#pragma unroll
    for (int m = 1; m < 32; m <<= 1) {
      a0 += __shfl_xor(a0, m, 64);
      a1 += __shfl_xor(a1, m, 64);
      a2 += __shfl_xor(a2, m, 64);
      a3 += __shfl_xor(a3, m, 64);
    }
    if (isred) {
      float gi = sigm(xwv0 + a0);
      float gf = sigm(xwv1 + a1);
      float gg = tanh_(xwv2 + a2);
      float go = sigm(xwv3 + a3);
      creg = gf * creg + gi * gg;
      float h = go * tanh_(creg);
      unsigned hb = (unsigned)__builtin_bit_cast(unsigned short, (_Float16)h);
      st_llc_u32(tago + (size_t)t * 640 + dim, ((unsigned)(t + 1) << 16) | hb);
      if (layer == 2) hs2[(size_t)t * 640 + dim] = h;  // plain store for GCN
    }
    // no end barrier: double-buffered LDS + next step's __syncthreads suffice
  }
}

// ---------------- CSR build (edges + self-loops), degrees ------------------
#define NE 16384
#define NN 1024
#define NET (NE + NN)

__global__ void k_csr_count(const int* __restrict__ ei, int* __restrict__ cnt) {
  int i = blockIdx.x * 256 + threadIdx.x;
  if (i >= NET) return;
  int d = (i < NE) ? ei[NE + i] : (i - NE);
  atomicAdd(&cnt[d], 1);
}

__global__ __launch_bounds__(1024) void k_csr_scan(
    const int* __restrict__ cnt, int* __restrict__ offs,
    float* __restrict__ dinv) {
  __shared__ int sd[1024];
  int tid = threadIdx.x;
  int v = cnt[tid];
  dinv[tid] = rsqrtf((float)v);  // deg >= 1 via self-loops
  sd[tid] = v;
  __syncthreads();
  for (int o = 1; o < 1024; o <<= 1) {
    int t = (tid >= o) ? sd[tid - o] : 0;
    __syncthreads();
    sd[tid] += t;
    __syncthreads();
  }
  if (tid == 0) offs[0] = 0;
  offs[tid + 1] = sd[tid];
}

__global__ void k_csr_fill(const int* __restrict__ ei, const int* __restrict__ offs,
                           int* __restrict__ fillc, const float* __restrict__ dinv,
                           int* __restrict__ asrc, float* __restrict__ anrm) {
  int i = blockIdx.x * 256 + threadIdx.x;
  if (i >= NET) return;
  int s, d;
  if (i < NE) { s = ei[i]; d = ei[NE + i]; }
  else        { s = d = i - NE; }
  int pos = offs[d] + atomicAdd(&fillc[d], 1);
  asrc[pos] = s;
  anrm[pos] = dinv[s] * dinv[d];
}

// ---------------- small fp32 GEMM with optional fused input-BN -------------
// C[M,N] = BN(A)[M,K] * W[K,N]; BN(A)=(A-mean[k])*rstd[k] when mean!=nullptr
__global__ void k_gemm_f32(const float* __restrict__ A, const float* __restrict__ W,
                           float* __restrict__ C, int M, int K, int N,
                           const float* __restrict__ mean,
                           const float* __restrict__ rstd) {
  int n = blockIdx.x * 64 + threadIdx.x;
  int m = blockIdx.y * 4 + threadIdx.y;
  if (n >= N || m >= M) return;
  const float* ar = A + (size_t)m * K;
  float acc = 0.0f;
  if (mean) {
#pragma unroll 4
    for (int k = 0; k < K; ++k)
      acc = fmaf((ar[k] - mean[k]) * rstd[k], W[(size_t)k * N + n], acc);
  } else {
#pragma unroll 4
    for (int k = 0; k < K; ++k) acc = fmaf(ar[k], W[(size_t)k * N + n], acc);
  }
  C[(size_t)m * N + n] = acc;
}

// ---------------- GCN aggregation (gather over CSR) + bias + leaky ---------
__global__ void k_gcn_agg(const float* __restrict__ h, const int* __restrict__ asrc,
                          const float* __restrict__ anrm, const int* __restrict__ offs,
                          const float* __restrict__ b, float* __restrict__ out,
                          int F) {
  int n = blockIdx.x, f = threadIdx.x;
  if (f >= F) return;
  int e0 = offs[n], e1 = offs[n + 1];
  float acc = 0.0f;
  for (int e = e0; e < e1; ++e)
    acc = fmaf(anrm[e], h[(size_t)asrc[e] * F + f], acc);
  acc += b[f];
  out[(size_t)n * F + f] = acc > 0.0f ? acc : 0.01f * acc;
}

// ---------------- batch norm stats (train-mode, biased var) ----------------
__global__ void k_bn_stats(const float* __restrict__ x, float* __restrict__ mean,
                           float* __restrict__ rstd, int F) {
  int f = blockIdx.x, tid = threadIdx.x;  // 256 threads
  float s = 0, s2 = 0;
  for (int n = tid; n < 1024; n += 256) {
    float v = x[(size_t)n * F + f];
    s += v;
    s2 += v * v;
  }
#pragma unroll
  for (int m = 1; m < 64; m <<= 1) {
    s += __shfl_xor(s, m, 64);
    s2 += __shfl_xor(s2, m, 64);
  }
  __shared__ float ls[4], ls2[4];
  int wv = tid >> 6;
  if ((tid & 63) == 0) { ls[wv] = s; ls2[wv] = s2; }
  __syncthreads();
  if (tid == 0) {
    float S = ls[0] + ls[1] + ls[2] + ls[3];
    float S2 = ls2[0] + ls2[1] + ls2[2] + ls2[3];
    float mu = S * (1.0f / 1024.0f);
    float var = S2 * (1.0f / 1024.0f) - mu * mu;
    mean[f] = mu;
    rstd[f] = rsqrtf(var + 1e-5f);
  }
}

// ---------------- segment_sum (of BN'd x) + concat + 3x FC -----------------
__global__ __launch_bounds__(1024) void k_segfcn(
    const float* __restrict__ x,  // [1024][50] pre-BN
    const float* __restrict__ mean, const float* __restrict__ rstd,  // [50]
    const float* __restrict__ gender, const float* __restrict__ handed,
    const float* __restrict__ W1, const float* __restrict__ b1,   // [32][52]
    const float* __restrict__ W2, const float* __restrict__ b2,   // [16][32]
    const float* __restrict__ W3, const float* __restrict__ b3,   // [1][16]
    float* __restrict__ out) {
  __shared__ float seg[16][52];
  __shared__ float y1[16][32];
  __shared__ float y2[16][16];
  int tid = threadIdx.x;
  if (tid < 800) {
    int g = tid / 50, f = tid % 50;
    float s = 0;
    for (int i = 0; i < 64; ++i) s += x[(size_t)(g * 64 + i) * 50 + f];
    seg[g][f] = (s - 64.0f * mean[f]) * rstd[f];  // BN is linear in the sum
  }
  if (tid < 16) { seg[tid][50] = gender[tid]; seg[tid][51] = handed[tid]; }
  __syncthreads();
  if (tid < 512) {
    int g = tid >> 5, o = tid & 31;
    float s = b1[o];
    for (int k = 0; k < 52; ++k) s += seg[g][k] * W1[o * 52 + k];
    y1[g][o] = s;
  }
  __syncthreads();
  if (tid < 256) {
    int g = tid >> 4, o = tid & 15;
    float s = b2[o];
    for (int k = 0; k < 32; ++k) s += y1[g][k] * W2[o * 32 + k];
    y2[g][o] = s;
  }
  __syncthreads();
  if (tid < 16) {
    float s = b3[0];
    for (int k = 0; k < 16; ++k) s += y2[tid][k] * W3[k];
    out[tid] = s;
  }
}

// ---------------------------------------------------------------------------
extern "C" void kernel_launch(void* const* d_in, const int* in_sizes, int n_in,
                              void* d_out, int out_size, void* d_ws, size_t ws_size,
                              hipStream_t stream) {
  const float* x_in   = (const float*)d_in[0];
  const int*   ei     = (const int*)d_in[1];
  const float* gender = (const float*)d_in[2];
  const float* handed = (const float*)d_in[3];
  const float* Wih[3] = {(const float*)d_in[4],  (const float*)d_in[8],  (const float*)d_in[12]};
  const float* Whh[3] = {(const float*)d_in[5],  (const float*)d_in[9],  (const float*)d_in[13]};
  const float* bih[3] = {(const float*)d_in[6],  (const float*)d_in[10], (const float*)d_in[14]};
  const float* bhh[3] = {(const float*)d_in[7],  (const float*)d_in[11], (const float*)d_in[15]};
  const float* gW[4]  = {(const float*)d_in[16], (const float*)d_in[18], (const float*)d_in[20], (const float*)d_in[22]};
  const float* gb[4]  = {(const float*)d_in[17], (const float*)d_in[19], (const float*)d_in[21], (const float*)d_in[23]};
  const float* fW[3]  = {(const float*)d_in[24], (const float*)d_in[26], (const float*)d_in[28]};
  const float* fb[3]  = {(const float*)d_in[25], (const float*)d_in[27], (const float*)d_in[29]};
  float* out = (float*)d_out;

  // workspace layout
  char* ws = (char*)d_ws;
  size_t off = 0;
  auto alloc = [&](size_t bytes) -> void* {
    void* p = ws + off;
    off = (off + bytes + 255) & ~(size_t)255;
    return p;
  };
  const int KP0 = 8512;  // 8500 padded to /32
  f16*   X16   = (f16*)alloc((size_t)1024 * KP0 * 2);
  f16*   W016  = (f16*)alloc((size_t)2560 * KP0 * 2);
  f16*   W116  = (f16*)alloc((size_t)2560 * 640 * 2);
  f16*   W216  = (f16*)alloc((size_t)2560 * 640 * 2);
  float* BSUM  = (float*)alloc(3 * 2560 * 4);
  float* XW    = (float*)alloc((size_t)1024 * 2560 * 4);
  unsigned* TAGA = (unsigned*)alloc((size_t)3 * 1024 * 640 * 4);  // 3 tag bufs
  float* HS2   = (float*)alloc((size_t)1024 * 640 * 4);
  float* GA    = (float*)alloc((size_t)1024 * 320 * 4);
  float* GB    = (float*)alloc((size_t)1024 * 320 * 4);
  int*   CNT   = (int*)alloc(1024 * 4);
  int*   OFFS  = (int*)alloc(1025 * 4);
  int*   FILLC = (int*)alloc(1024 * 4);
  float* DINV  = (float*)alloc(1024 * 4);
  int*   ASRC  = (int*)alloc(NET * 4);
  float* ANRM  = (float*)alloc(NET * 4);
  float* MEAN  = (float*)alloc(320 * 4);
  float* RSTD  = (float*)alloc(320 * 4);
  unsigned* TAG0 = TAGA;
  unsigned* TAG1 = TAGA + (size_t)1024 * 640;
  unsigned* TAG2 = TAGA + (size_t)2 * 1024 * 640;
  (void)ws_size; (void)in_sizes; (void)n_in; (void)out_size;

  // conversions & bias sums
  k_cvt_pad<<<dim3(34, 1024), 256, 0, stream>>>(x_in, X16, 8500, KP0);
  k_cvt_pad<<<dim3(34, 2560), 256, 0, stream>>>(Wih[0], W016, 8500, KP0);
  k_cvt_pad<<<dim3(3, 2560), 256, 0, stream>>>(Wih[1], W116, 640, 640);
  k_cvt_pad<<<dim3(3, 2560), 256, 0, stream>>>(Wih[2], W216, 640, 640);
  for (int l = 0; l < 3; ++l)
    k_vadd<<<10, 256, 0, stream>>>(bih[l], bhh[l], BSUM + l * 2560, 2560);

  // zero CSR counters and tag buffers (ws poisoned 0xAA each timed call;
  // tag 0 never matches expected tags 1..1024)
  k_zero<<<5, 256, 0, stream>>>(CNT, 1024);
  k_zero<<<5, 256, 0, stream>>>(FILLC, 1024);
  k_zero<<<7680, 256, 0, stream>>>((int*)TAGA, 3 * 1024 * 640);

  // CSR build
  k_csr_count<<<68, 256, 0, stream>>>(ei, CNT);
  k_csr_scan<<<1, 1024, 0, stream>>>(CNT, OFFS, DINV);
  k_csr_fill<<<68, 256, 0, stream>>>(ei, OFFS, FILLC, DINV, ASRC, ANRM);

  // layer-0 input projection (K=8512 f16 MFMA GEMM), then fused 3-layer LSTM
  k_gemm_bt_f16<<<dim3(20, 8), 256, 0, stream>>>(X16, W016, BSUM, XW, 1024, 2560, KP0);
  k_lstm3<<<3 * RPL, 512, 0, stream>>>(Whh[0], Whh[1], Whh[2],
                                       W116, W216, XW, BSUM,
                                       TAG0, TAG1, TAG2, HS2);

  // GCN stack (BN-apply fused into the NEXT kernel's operand read)
  const float* gin = HS2;
  int Fin = 640;
  const int Fo[4] = {320, 180, 90, 50};
  for (int l = 0; l < 4; ++l) {
    int F = Fo[l];
    const float* mn = (l == 0) ? nullptr : MEAN;  // layer0 input has no BN
    k_gemm_f32<<<dim3((F + 63) / 64, 256), dim3(64, 4), 0, stream>>>(
        gin, gW[l], GA, 1024, Fin, F, mn, RSTD);
    k_gcn_agg<<<1024, ((F + 63) / 64) * 64, 0, stream>>>(GA, ASRC, ANRM, OFFS, gb[l], GB, F);
    k_bn_stats<<<F, 256, 0, stream>>>(GB, MEAN, RSTD, F);
    gin = GB;
    Fin = F;
  }

  // readout (applies the last BN inside)
  k_segfcn<<<1, 1024, 0, stream>>>(GB, MEAN, RSTD, gender, handed,
                                   fW[0], fb[0], fW[1], fb[1], fW[2], fb[2], out);
}